// Round 5
// baseline (248.087 us; speedup 1.0000x reference)
//
#include <hip/hip_runtime.h>
#include <math.h>

// Problem constants
constexpr int D      = 1024;
constexpr int H      = 16;
constexpr int DH     = 64;
constexpr int Bb     = 2;
constexpr int T      = 2048;
constexpr int BT     = Bb * T;       // 4096
constexpr int CHUNK  = 64;
constexpr int NC     = T / CHUNK;    // 32
constexpr int LS     = 72;           // LDS row stride in shorts

typedef __attribute__((ext_vector_type(8))) short bf16x8;
typedef __attribute__((ext_vector_type(4))) float f32x4;

#define GLOAD_LDS16(gp, lp) \
    __builtin_amdgcn_global_load_lds((const __attribute__((address_space(1))) void*)(gp), \
                                     (__attribute__((address_space(3))) void*)(lp), 16, 0, 0)

__device__ __forceinline__ short to_bf16(float f) {
    unsigned u = __float_as_uint(f);
    unsigned r = (u + 0x7fffu + ((u >> 16) & 1u)) >> 16;
    return (short)r;
}
__device__ __forceinline__ float bf2f(short s) {
    return __uint_as_float(((unsigned)(unsigned short)s) << 16);
}

__device__ __forceinline__ float block_sum_256(float v, float* sbuf) {
    #pragma unroll
    for (int off = 32; off > 0; off >>= 1) v += __shfl_down(v, off, 64);
    int lane = threadIdx.x & 63;
    int wid  = threadIdx.x >> 6;
    if (lane == 0) sbuf[wid] = v;
    __syncthreads();
    float r = (threadIdx.x < 4) ? sbuf[threadIdx.x] : 0.0f;
    r += __shfl_down(r, 2, 64);
    r += __shfl_down(r, 1, 64);
    if (threadIdx.x == 0) sbuf[0] = r;
    __syncthreads();
    float outv = sbuf[0];
    __syncthreads();
    return outv;
}

__device__ __forceinline__ float elu1(float x) {
    return x > 0.0f ? x + 1.0f : expf(x);
}

// ---------------------------------------------------------------------------
// Merged prologue: blocks [0,BT) do LayerNorm rows; [BT, BT+5120) do the
// three weight transposes (fp32 -> bf16, [K,N] -> [N,K]).
// ---------------------------------------------------------------------------
__global__ __launch_bounds__(256) void pre_kernel(const float* __restrict__ x,
                                                  const float* __restrict__ g,
                                                  const float* __restrict__ b,
                                                  const float* __restrict__ wq,
                                                  const float* __restrict__ wg,
                                                  const float* __restrict__ wp,
                                                  short* __restrict__ ynb,
                                                  short* __restrict__ xbb,
                                                  short* __restrict__ wTcomb,
                                                  short* __restrict__ wTp) {
    __shared__ float sbuf[4];
    __shared__ short tile[32][33];
    int bid = blockIdx.x;
    if (bid < BT) {
        int row = bid;
        const float* xr = x + (size_t)row * D;
        int c = threadIdx.x * 4;
        float4 xv = *(const float4*)(xr + c);
        float mu = block_sum_256(xv.x + xv.y + xv.z + xv.w, sbuf) * (1.0f / D);
        float d0 = xv.x - mu, d1 = xv.y - mu, d2 = xv.z - mu, d3 = xv.w - mu;
        float var = block_sum_256(d0*d0 + d1*d1 + d2*d2 + d3*d3, sbuf) * (1.0f / D);
        float rstd = rsqrtf(var + 1e-5f);
        float4 gv = *(const float4*)(g + c);
        float4 bv = *(const float4*)(b + c);
        short4 o, xo;
        o.x = to_bf16(d0 * rstd * gv.x + bv.x);
        o.y = to_bf16(d1 * rstd * gv.y + bv.y);
        o.z = to_bf16(d2 * rstd * gv.z + bv.z);
        o.w = to_bf16(d3 * rstd * gv.w + bv.w);
        xo.x = to_bf16(xv.x); xo.y = to_bf16(xv.y);
        xo.z = to_bf16(xv.z); xo.w = to_bf16(xv.w);
        *(short4*)(ynb + (size_t)row * D + c) = o;
        *(short4*)(xbb + (size_t)row * D + c) = xo;
    } else {
        int t2 = bid - BT;
        const float* W; short* Wt; int N; int t;
        if (t2 < 3072)      { W = wq; Wt = wTcomb;                       N = 3072; t = t2; }
        else if (t2 < 4096) { W = wg; Wt = wTcomb + (size_t)3072 * 1024; N = 1024; t = t2 - 3072; }
        else                { W = wp; Wt = wTp;                          N = 1024; t = t2 - 4096; }
        int ntiles = N >> 5;
        int nb = (t % ntiles) * 32, kb = (t / ntiles) * 32;
        int tx = threadIdx.x & 31, ty = threadIdx.x >> 5;
        #pragma unroll
        for (int i = 0; i < 4; ++i) {
            int k = kb + ty + i * 8;
            tile[ty + i * 8][tx] = to_bf16(W[(size_t)k * N + nb + tx]);
        }
        __syncthreads();
        #pragma unroll
        for (int i = 0; i < 4; ++i) {
            int n = nb + ty + i * 8;
            Wt[(size_t)n * 1024 + kb + tx] = tile[tx][ty + i * 8];
        }
    }
}

// ---------------------------------------------------------------------------
// Combined qkv+gate GEMM, BK=64: N = 4096 (cols [0,3D)=qkv from x_norm,
// [3D,4D)=gate from raw x). All outputs bf16.
// ---------------------------------------------------------------------------
__global__ __launch_bounds__(256) void gemm_fused_qkvgate(const short* __restrict__ xnb,
                                                          const short* __restrict__ xb,
                                                          const short* __restrict__ Wt,
                                                          const float* __restrict__ b_qkv,
                                                          const float* __restrict__ b_gate,
                                                          short* __restrict__ qkvb,
                                                          short* __restrict__ gateb) {
    constexpr int BK = 64, K = 1024;
    __shared__ short Als[128 * BK];   // 16 KB
    __shared__ short Bls[128 * BK];   // 16 KB

    const int tid  = threadIdx.x;
    const int wave = tid >> 6;
    const int lane = tid & 63;
    const int row0 = blockIdx.y * 128;
    const int col0 = blockIdx.x * 128;
    const bool isg = (col0 >= 3 * D);
    const short* A = isg ? xb : xnb;
    const int wm = (wave & 1) * 64;
    const int wn = (wave >> 1) * 64;

    f32x4 acc[4][4] = {};
    const int srow = lane >> 3;          // 0..7 (row within 8-row chunk)
    const int skk  = (lane & 7) * 8;     // 0..56 shorts (16B granules)
    const int fr = lane & 15;
    const int fk = (lane >> 4) * 8;

    for (int k0 = 0; k0 < K; k0 += BK) {
        __syncthreads();
        #pragma unroll
        for (int u = 0; u < 4; ++u) {
            int cchunk = wave * 4 + u;               // 0..15, 8 rows each
            int r = cchunk * 8 + srow;
            GLOAD_LDS16(A  + (size_t)(row0 + r) * K + k0 + skk, &Als[cchunk * 512]);
            GLOAD_LDS16(Wt + (size_t)(col0 + r) * K + k0 + skk, &Bls[cchunk * 512]);
        }
        __syncthreads();

        #pragma unroll
        for (int h = 0; h < 2; ++h) {
            bf16x8 af[4], bfr[4];
            #pragma unroll
            for (int i = 0; i < 4; ++i) {
                af[i]  = *(const bf16x8*)&Als[(wm + i * 16 + fr) * BK + h * 32 + fk];
                bfr[i] = *(const bf16x8*)&Bls[(wn + i * 16 + fr) * BK + h * 32 + fk];
            }
            #pragma unroll
            for (int mi = 0; mi < 4; ++mi)
                #pragma unroll
                for (int ni = 0; ni < 4; ++ni)
                    acc[mi][ni] = __builtin_amdgcn_mfma_f32_16x16x32_bf16(af[mi], bfr[ni], acc[mi][ni], 0, 0, 0);
        }
    }

    const int ccol  = lane & 15;
    const int crow4 = (lane >> 4) * 4;
    const float* biasp = isg ? (b_gate - 3 * D) : b_qkv;
    short* dst  = isg ? gateb : qkvb;
    const int stride = isg ? D : 3 * D;
    const int csub   = isg ? 3 * D : 0;
    #pragma unroll
    for (int mi = 0; mi < 4; ++mi) {
        #pragma unroll
        for (int ni = 0; ni < 4; ++ni) {
            int col = col0 + wn + ni * 16 + ccol;
            float bv = biasp[col];
            #pragma unroll
            for (int r = 0; r < 4; ++r) {
                int row = row0 + wm + mi * 16 + crow4 + r;
                dst[(size_t)row * stride + (col - csub)] = to_bf16(acc[mi][ni][r] + bv);
            }
        }
    }
}

// ---------------------------------------------------------------------------
// Gate apply, in place on bf16 qkv.
// ---------------------------------------------------------------------------
__global__ __launch_bounds__(256) void gate_apply_inplace(short* __restrict__ qkvb,
                                                          const short* __restrict__ gateb) {
    __shared__ float sbuf[4];
    int row = blockIdx.x;
    int c = threadIdx.x * 4;
    short4 gl = *(const short4*)(gateb + (size_t)row * D + c);
    float s0 = 1.0f / (1.0f + expf(-bf2f(gl.x)));
    float s1 = 1.0f / (1.0f + expf(-bf2f(gl.y)));
    float s2 = 1.0f / (1.0f + expf(-bf2f(gl.z)));
    float s3 = 1.0f / (1.0f + expf(-bf2f(gl.w)));
    float mean = block_sum_256(s0 + s1 + s2 + s3, sbuf) * (1.0f / D);
    float inv = 1.0f / (mean + 1e-5f);
    float g0 = s0 * inv, g1 = s1 * inv, g2 = s2 * inv, g3 = s3 * inv;

    short* qp = qkvb + (size_t)row * (3 * D) + c;
    short* kp = qp + D;
    short4 qv = *(short4*)qp;
    short4 kv = *(short4*)kp;
    qv.x = to_bf16(elu1(bf2f(qv.x) * g0)); qv.y = to_bf16(elu1(bf2f(qv.y) * g1));
    qv.z = to_bf16(elu1(bf2f(qv.z) * g2)); qv.w = to_bf16(elu1(bf2f(qv.w) * g3));
    kv.x = to_bf16(elu1(bf2f(kv.x) * g0)); kv.y = to_bf16(elu1(bf2f(kv.y) * g1));
    kv.z = to_bf16(elu1(bf2f(kv.z) * g2)); kv.w = to_bf16(elu1(bf2f(kv.w) * g3));
    *(short4*)qp = qv;
    *(short4*)kp = kv;
}

// ---------------------------------------------------------------------------
// Per-chunk state: Sc[m][d] = sum_t V[t][m] K[t][d] (fp32), zc[d] = sum_t K[t][d]
// ---------------------------------------------------------------------------
__global__ __launch_bounds__(256) void chunk_state_mfma(const short* __restrict__ qkvb,
                                                        float* __restrict__ Sc,
                                                        float* __restrict__ zc) {
    __shared__ short Kt[DH * LS];   // [d][t]
    __shared__ short Vt[DH * LS];   // [m][t]
    int idx = blockIdx.x;
    int c = idx & (NC - 1), h = (idx >> 5) & (H - 1), b = idx >> 9;
    size_t bt0 = (size_t)b * T + c * CHUNK;
    const short* kbase = qkvb + bt0 * (3 * D) + D + h * DH;
    const short* vbase = qkvb + bt0 * (3 * D) + 2 * D + h * DH;
    int tid = threadIdx.x;

    #pragma unroll
    for (int l = 0; l < 2; ++l) {
        int i  = tid + l * 256;
        int t  = i >> 3;
        int d8 = (i & 7) * 8;
        bf16x8 kv = *(const bf16x8*)(kbase + (size_t)t * (3 * D) + d8);
        bf16x8 vv = *(const bf16x8*)(vbase + (size_t)t * (3 * D) + d8);
        #pragma unroll
        for (int j = 0; j < 8; ++j) {
            Kt[(d8 + j) * LS + t] = kv[j];
            Vt[(d8 + j) * LS + t] = vv[j];
        }
    }
    __syncthreads();

    const int wv = tid >> 6, lane = tid & 63;
    const int fr = lane & 15, quad = lane >> 4;
    const int fk = quad * 8, crow4 = quad * 4, ccol = lane & 15;
    const int mbase = wv * 16;

    bf16x8 af[2];
    af[0] = *(const bf16x8*)&Vt[(mbase + fr) * LS + fk];
    af[1] = *(const bf16x8*)&Vt[(mbase + fr) * LS + 32 + fk];

    f32x4 acc[4] = {};
    #pragma unroll
    for (int n = 0; n < 4; ++n) {
        #pragma unroll
        for (int ck = 0; ck < 2; ++ck) {
            bf16x8 bk = *(const bf16x8*)&Kt[(n * 16 + fr) * LS + ck * 32 + fk];
            acc[n] = __builtin_amdgcn_mfma_f32_16x16x32_bf16(af[ck], bk, acc[n], 0, 0, 0);
        }
    }

    float* Sd = Sc + (size_t)idx * (DH * DH);
    #pragma unroll
    for (int n = 0; n < 4; ++n)
        #pragma unroll
        for (int r = 0; r < 4; ++r)
            Sd[(mbase + crow4 + r) * DH + n * 16 + ccol] = acc[n][r];

    if (tid < DH) {
        float zs = 0.0f;
        for (int t = 0; t < CHUNK; ++t) zs += bf2f(Kt[tid * LS + t]);
        zc[(size_t)idx * DH + tid] = zs;
    }
}

// ---------------------------------------------------------------------------
// Chunk attention with ON-THE-FLY exclusive prefix of Sc/zc (reads j<c from
// L2-resident per-(b,h) state array). Writes bf16 out for proj GEMM.
// ---------------------------------------------------------------------------
__global__ __launch_bounds__(256) void chunk_attn_mfma(const short* __restrict__ qkvb,
                                                       const float* __restrict__ Sc,
                                                       const float* __restrict__ zc,
                                                       short* __restrict__ attnb) {
    __shared__ short Qs[CHUNK * LS];   // [t][d]
    __shared__ short Ks[CHUNK * LS];   // [s][d]
    __shared__ short Vt[DH * LS];      // [m][s]
    __shared__ short Ss[DH * LS];      // [m][d]  (prefix state, bf16)
    __shared__ short As[CHUNK * LS];   // [t][s]
    __shared__ float zpL[DH];
    __shared__ float den[CHUNK];

    int idx = blockIdx.x;
    int c = idx & (NC - 1), h = (idx >> 5) & (H - 1), b = idx >> 9;
    size_t bt0 = (size_t)b * T + c * CHUNK;
    const short* qbase = qkvb + bt0 * (3 * D) + h * DH;
    const short* kbase = qbase + D;
    const short* vbase = qbase + 2 * D;
    int tid = threadIdx.x;

    #pragma unroll
    for (int l = 0; l < 2; ++l) {
        int i  = tid + l * 256;
        int t  = i >> 3;
        int d8 = (i & 7) * 8;
        *(bf16x8*)&Qs[t * LS + d8] = *(const bf16x8*)(qbase + (size_t)t * (3 * D) + d8);
        *(bf16x8*)&Ks[t * LS + d8] = *(const bf16x8*)(kbase + (size_t)t * (3 * D) + d8);
        bf16x8 vv = *(const bf16x8*)(vbase + (size_t)t * (3 * D) + d8);
        #pragma unroll
        for (int j = 0; j < 8; ++j) Vt[(d8 + j) * LS + t] = vv[j];
    }

    // exclusive prefix of S over chunks j < c: each thread owns 16 elements
    {
        float acc16[16] = {};
        const float* Sbh = Sc + (size_t)(idx - c) * (DH * DH);
        for (int j = 0; j < c; ++j) {
            const float* Sj = Sbh + (size_t)j * (DH * DH) + tid * 16;
            #pragma unroll
            for (int q4 = 0; q4 < 4; ++q4) {
                float4 v4 = *(const float4*)(Sj + q4 * 4);
                acc16[q4 * 4 + 0] += v4.x;
                acc16[q4 * 4 + 1] += v4.y;
                acc16[q4 * 4 + 2] += v4.z;
                acc16[q4 * 4 + 3] += v4.w;
            }
        }
        int m0 = tid >> 2, d0 = (tid & 3) * 16;
        bf16x8 s0v, s1v;
        #pragma unroll
        for (int jj = 0; jj < 8; ++jj) {
            s0v[jj] = to_bf16(acc16[jj]);
            s1v[jj] = to_bf16(acc16[8 + jj]);
        }
        *(bf16x8*)&Ss[m0 * LS + d0]     = s0v;
        *(bf16x8*)&Ss[m0 * LS + d0 + 8] = s1v;
    }
    if (tid < DH) {
        float zpv = 0.0f;
        const float* zbh = zc + (size_t)(idx - c) * DH + tid;
        for (int j = 0; j < c; ++j) zpv += zbh[(size_t)j * DH];
        zpL[tid] = zpv;
    }
    __syncthreads();

    const int wv = tid >> 6, lane = tid & 63;
    const int fr = lane & 15, quad = lane >> 4;
    const int fk = quad * 8, crow4 = quad * 4, ccol = lane & 15;
    const int tbase = wv * 16;

    bf16x8 aq[2];
    aq[0] = *(const bf16x8*)&Qs[(tbase + fr) * LS + fk];
    aq[1] = *(const bf16x8*)&Qs[(tbase + fr) * LS + 32 + fk];

    // scores C[t][s] = q_t . k_s
    f32x4 accs[4] = {};
    #pragma unroll
    for (int n = 0; n < 4; ++n) {
        #pragma unroll
        for (int ck = 0; ck < 2; ++ck) {
            bf16x8 bk = *(const bf16x8*)&Ks[(n * 16 + fr) * LS + ck * 32 + fk];
            accs[n] = __builtin_amdgcn_mfma_f32_16x16x32_bf16(aq[ck], bk, accs[n], 0, 0, 0);
        }
    }

    float part[4] = {0.f, 0.f, 0.f, 0.f};
    #pragma unroll
    for (int n = 0; n < 4; ++n) {
        #pragma unroll
        for (int r = 0; r < 4; ++r) {
            int tt = tbase + crow4 + r;
            int ss = n * 16 + ccol;
            float v = (ss <= tt) ? accs[n][r] : 0.0f;
            part[r] += v;
            As[tt * LS + ss] = to_bf16(v);
        }
    }
    #pragma unroll
    for (int r = 0; r < 4; ++r) {
        part[r] += __shfl_xor(part[r], 1, 64);
        part[r] += __shfl_xor(part[r], 2, 64);
        part[r] += __shfl_xor(part[r], 4, 64);
        part[r] += __shfl_xor(part[r], 8, 64);
    }
    if (fr == 0) {
        #pragma unroll
        for (int r = 0; r < 4; ++r) den[tbase + crow4 + r] = part[r];
    }
    __syncthreads();

    if (tid < CHUNK) {
        float qz = 0.0f;
        #pragma unroll 8
        for (int d = 0; d < DH; ++d) qz += bf2f(Qs[tid * LS + d]) * zpL[d];
        den[tid] += qz + 1e-5f;
    }

    // out C[t][m] = Q @ Sp + A @ V
    f32x4 acco[4] = {};
    #pragma unroll
    for (int m4 = 0; m4 < 4; ++m4) {
        #pragma unroll
        for (int ck = 0; ck < 2; ++ck) {
            bf16x8 bs = *(const bf16x8*)&Ss[(m4 * 16 + fr) * LS + ck * 32 + fk];
            acco[m4] = __builtin_amdgcn_mfma_f32_16x16x32_bf16(aq[ck], bs, acco[m4], 0, 0, 0);
        }
    }
    bf16x8 aa[2];
    aa[0] = *(const bf16x8*)&As[(tbase + fr) * LS + fk];
    aa[1] = *(const bf16x8*)&As[(tbase + fr) * LS + 32 + fk];
    #pragma unroll
    for (int m4 = 0; m4 < 4; ++m4) {
        #pragma unroll
        for (int ck = 0; ck < 2; ++ck) {
            bf16x8 bv = *(const bf16x8*)&Vt[(m4 * 16 + fr) * LS + ck * 32 + fk];
            acco[m4] = __builtin_amdgcn_mfma_f32_16x16x32_bf16(aa[ck], bv, acco[m4], 0, 0, 0);
        }
    }
    __syncthreads();

    short* obase = attnb + bt0 * D + h * DH;
    #pragma unroll
    for (int r = 0; r < 4; ++r) {
        int tt = tbase + crow4 + r;
        float rv = 1.0f / den[tt];
        #pragma unroll
        for (int m4 = 0; m4 < 4; ++m4)
            obase[(size_t)tt * D + m4 * 16 + ccol] = to_bf16(acco[m4][r] * rv);
    }
}

// ---------------------------------------------------------------------------
// Proj GEMM, BK=64: C[4096][1024] fp32 = A @ Bt^T + bias. 64x128 tile.
// ---------------------------------------------------------------------------
__global__ __launch_bounds__(256) void gemm_proj64(const short* __restrict__ A,
                                                   const short* __restrict__ Bt,
                                                   const float* __restrict__ bias,
                                                   float* __restrict__ C) {
    constexpr int BK = 64, K = 1024, N = 1024;
    __shared__ short Als[64 * BK];    // 8 KB
    __shared__ short Bls[128 * BK];   // 16 KB

    const int tid  = threadIdx.x;
    const int wave = tid >> 6;
    const int lane = tid & 63;
    const int row0 = blockIdx.y * 64;
    const int col0 = blockIdx.x * 128;
    const int wn = wave * 32;

    f32x4 acc[4][2] = {};
    const int srow = lane >> 3;
    const int skk  = (lane & 7) * 8;
    const int fr = lane & 15;
    const int fk = (lane >> 4) * 8;

    for (int k0 = 0; k0 < K; k0 += BK) {
        __syncthreads();
        #pragma unroll
        for (int u = 0; u < 6; ++u) {
            int cc = wave * 6 + u;   // 0..23; 0..7 -> A chunks, 8..23 -> B chunks
            if (cc < 8) {
                int r = cc * 8 + srow;
                GLOAD_LDS16(A + (size_t)(row0 + r) * K + k0 + skk, &Als[cc * 512]);
            } else {
                int c2 = cc - 8;
                int r = c2 * 8 + srow;
                GLOAD_LDS16(Bt + (size_t)(col0 + r) * K + k0 + skk, &Bls[c2 * 512]);
            }
        }
        __syncthreads();

        #pragma unroll
        for (int h = 0; h < 2; ++h) {
            bf16x8 af[4], bfr[2];
            #pragma unroll
            for (int i = 0; i < 4; ++i)
                af[i] = *(const bf16x8*)&Als[(i * 16 + fr) * BK + h * 32 + fk];
            #pragma unroll
            for (int j = 0; j < 2; ++j)
                bfr[j] = *(const bf16x8*)&Bls[(wn + j * 16 + fr) * BK + h * 32 + fk];
            #pragma unroll
            for (int mi = 0; mi < 4; ++mi)
                #pragma unroll
                for (int ni = 0; ni < 2; ++ni)
                    acc[mi][ni] = __builtin_amdgcn_mfma_f32_16x16x32_bf16(af[mi], bfr[ni], acc[mi][ni], 0, 0, 0);
        }
    }

    const int ccol  = lane & 15;
    const int crow4 = (lane >> 4) * 4;
    #pragma unroll
    for (int mi = 0; mi < 4; ++mi) {
        #pragma unroll
        for (int ni = 0; ni < 2; ++ni) {
            int col = col0 + wn + ni * 16 + ccol;
            float bv = bias[col];
            #pragma unroll
            for (int r = 0; r < 4; ++r) {
                int row = row0 + mi * 16 + crow4 + r;
                C[(size_t)row * N + col] = acc[mi][ni][r] + bv;
            }
        }
    }
}

// ---------------------------------------------------------------------------
extern "C" void kernel_launch(void* const* d_in, const int* in_sizes, int n_in,
                              void* d_out, int out_size, void* d_ws, size_t ws_size,
                              hipStream_t stream) {
    const float* x      = (const float*)d_in[0];
    const float* ln_g   = (const float*)d_in[1];
    const float* ln_b   = (const float*)d_in[2];
    const float* w_qkv  = (const float*)d_in[3];
    const float* b_qkv  = (const float*)d_in[4];
    const float* w_gate = (const float*)d_in[5];
    const float* b_gate = (const float*)d_in[6];
    const float* w_proj = (const float*)d_in[7];
    const float* b_proj = (const float*)d_in[8];
    float* out = (float*)d_out;

    short* xnb   = (short*)d_ws;                       // BT*D bf16 (8 MB)  [dead after GEMM]
    short* xb    = xnb + (size_t)BT * D;               // BT*D bf16 (8 MB)  [dead after GEMM]
    short* wTc   = xb + (size_t)BT * D;                // 4096*1024 bf16 (8 MB) [dead after GEMM]
    short* wTp   = wTc + (size_t)4096 * 1024;          // D*D bf16 (2 MB)
    short* qkvb  = wTp + (size_t)D * D;                // BT*3D bf16 (24 MB)
    short* gateb = qkvb + (size_t)BT * 3 * D;          // BT*D bf16 (8 MB)  [dead after gate_apply]
    short* attnb = gateb + (size_t)BT * D;             // BT*D bf16 (8 MB)
    float* zc    = (float*)(attnb + (size_t)BT * D);   // Bb*H*NC*DH fp32 (256 KB)
    float* Sc    = (float*)xnb;                        // Bb*H*NC*DH*DH fp32 (16 MB), aliases xnb+xb

    pre_kernel<<<BT + 5120, 256, 0, stream>>>(x, ln_g, ln_b, w_qkv, w_gate, w_proj,
                                              xnb, xb, wTc, wTp);
    gemm_fused_qkvgate<<<dim3(32, 32), 256, 0, stream>>>(
        xnb, xb, wTc, b_qkv, b_gate, qkvb, gateb);
    gate_apply_inplace<<<BT, 256, 0, stream>>>(qkvb, gateb);
    chunk_state_mfma<<<Bb * H * NC, 256, 0, stream>>>(qkvb, Sc, zc);
    chunk_attn_mfma<<<Bb * H * NC, 256, 0, stream>>>(qkvb, Sc, zc, attnb);
    gemm_proj64<<<dim3(D / 128, BT / 64), 256, 0, stream>>>(attnb, wTp, b_proj, out);
}

// Round 6
// 222.968 us; speedup vs baseline: 1.1127x; 1.1127x over previous
//
#include <hip/hip_runtime.h>
#include <math.h>

// Problem constants
constexpr int D      = 1024;
constexpr int H      = 16;
constexpr int DH     = 64;
constexpr int Bb     = 2;
constexpr int T      = 2048;
constexpr int BT     = Bb * T;       // 4096
constexpr int CHUNK  = 64;
constexpr int NC     = T / CHUNK;    // 32
constexpr int LS     = 72;           // LDS row stride (shorts) for chunk kernels

typedef __attribute__((ext_vector_type(8))) short bf16x8;
typedef __attribute__((ext_vector_type(4))) float f32x4;

#define GLOAD_LDS16(gp, lp) \
    __builtin_amdgcn_global_load_lds((const __attribute__((address_space(1))) void*)(gp), \
                                     (__attribute__((address_space(3))) void*)(lp), 16, 0, 0)

__device__ __forceinline__ short to_bf16(float f) {
    unsigned u = __float_as_uint(f);
    unsigned r = (u + 0x7fffu + ((u >> 16) & 1u)) >> 16;
    return (short)r;
}
__device__ __forceinline__ float bf2f(short s) {
    return __uint_as_float(((unsigned)(unsigned short)s) << 16);
}

__device__ __forceinline__ float block_sum_256(float v, float* sbuf) {
    #pragma unroll
    for (int off = 32; off > 0; off >>= 1) v += __shfl_down(v, off, 64);
    int lane = threadIdx.x & 63;
    int wid  = threadIdx.x >> 6;
    if (lane == 0) sbuf[wid] = v;
    __syncthreads();
    float r = (threadIdx.x < 4) ? sbuf[threadIdx.x] : 0.0f;
    r += __shfl_down(r, 2, 64);
    r += __shfl_down(r, 1, 64);
    if (threadIdx.x == 0) sbuf[0] = r;
    __syncthreads();
    float outv = sbuf[0];
    __syncthreads();
    return outv;
}

__device__ __forceinline__ float elu1(float x) {
    return x > 0.0f ? x + 1.0f : __expf(x);
}

// ---------------------------------------------------------------------------
// Merged prologue: blocks [0,BT): LayerNorm + zero gmean[row];
// [BT, BT+5120): three weight transposes (fp32 -> bf16, [K,N] -> [N,K]).
// ---------------------------------------------------------------------------
__global__ __launch_bounds__(256) void pre_kernel(const float* __restrict__ x,
                                                  const float* __restrict__ g,
                                                  const float* __restrict__ b,
                                                  const float* __restrict__ wq,
                                                  const float* __restrict__ wg,
                                                  const float* __restrict__ wp,
                                                  short* __restrict__ ynb,
                                                  short* __restrict__ xbb,
                                                  short* __restrict__ wTcomb,
                                                  short* __restrict__ wTp,
                                                  float* __restrict__ gmean) {
    __shared__ float sbuf[4];
    __shared__ short tile[32][33];
    int bid = blockIdx.x;
    if (bid < BT) {
        int row = bid;
        if (threadIdx.x == 0) gmean[row] = 0.0f;
        const float* xr = x + (size_t)row * D;
        int c = threadIdx.x * 4;
        float4 xv = *(const float4*)(xr + c);
        float mu = block_sum_256(xv.x + xv.y + xv.z + xv.w, sbuf) * (1.0f / D);
        float d0 = xv.x - mu, d1 = xv.y - mu, d2 = xv.z - mu, d3 = xv.w - mu;
        float var = block_sum_256(d0*d0 + d1*d1 + d2*d2 + d3*d3, sbuf) * (1.0f / D);
        float rstd = rsqrtf(var + 1e-5f);
        float4 gv = *(const float4*)(g + c);
        float4 bv = *(const float4*)(b + c);
        short4 o, xo;
        o.x = to_bf16(d0 * rstd * gv.x + bv.x);
        o.y = to_bf16(d1 * rstd * gv.y + bv.y);
        o.z = to_bf16(d2 * rstd * gv.z + bv.z);
        o.w = to_bf16(d3 * rstd * gv.w + bv.w);
        xo.x = to_bf16(xv.x); xo.y = to_bf16(xv.y);
        xo.z = to_bf16(xv.z); xo.w = to_bf16(xv.w);
        *(short4*)(ynb + (size_t)row * D + c) = o;
        *(short4*)(xbb + (size_t)row * D + c) = xo;
    } else {
        int t2 = bid - BT;
        const float* W; short* Wt; int N; int t;
        if (t2 < 3072)      { W = wq; Wt = wTcomb;                       N = 3072; t = t2; }
        else if (t2 < 4096) { W = wg; Wt = wTcomb + (size_t)3072 * 1024; N = 1024; t = t2 - 3072; }
        else                { W = wp; Wt = wTp;                          N = 1024; t = t2 - 4096; }
        int ntiles = N >> 5;
        int nb = (t % ntiles) * 32, kb = (t / ntiles) * 32;
        int tx = threadIdx.x & 31, ty = threadIdx.x >> 5;
        #pragma unroll
        for (int i = 0; i < 4; ++i) {
            int k = kb + ty + i * 8;
            tile[ty + i * 8][tx] = to_bf16(W[(size_t)k * N + nb + tx]);
        }
        __syncthreads();
        #pragma unroll
        for (int i = 0; i < 4; ++i) {
            int n = nb + ty + i * 8;
            Wt[(size_t)n * 1024 + kb + tx] = tile[tx][ty + i * 8];
        }
    }
}

// ---------------------------------------------------------------------------
// Combined qkv+gate GEMM, BK=32, XOR-swizzled LDS (granule p = q ^ ((row>>1)&3)).
// cols [0,3D): qkv from x_norm -> bf16 qkvb.
// cols [3D,4D): gate from raw x -> sigmoid -> bf16 sigb + per-row fp32 sums
// atomically accumulated into gmean.
// ---------------------------------------------------------------------------
__global__ __launch_bounds__(256) void gemm_fused_qkvgate(const short* __restrict__ xnb,
                                                          const short* __restrict__ xb,
                                                          const short* __restrict__ Wt,
                                                          const float* __restrict__ b_qkv,
                                                          const float* __restrict__ b_gate,
                                                          short* __restrict__ qkvb,
                                                          short* __restrict__ sigb,
                                                          float* __restrict__ gmean) {
    constexpr int BK = 32, K = 1024;
    __shared__ short Als[128 * BK];   // 8 KB
    __shared__ short Bls[128 * BK];   // 8 KB
    __shared__ float gsum[128];

    const int tid  = threadIdx.x;
    const int wave = tid >> 6;
    const int lane = tid & 63;
    const int row0 = blockIdx.y * 128;
    const int col0 = blockIdx.x * 128;
    const bool isg = (col0 >= 3 * D);
    const short* A = isg ? xb : xnb;
    const int wm = (wave & 1) * 64;
    const int wn = (wave >> 1) * 64;

    if (isg && tid < 128) gsum[tid] = 0.0f;

    f32x4 acc[4][4] = {};
    const int srow = lane >> 2;                                  // 0..15
    const int skk  = (((lane & 3) ^ ((lane >> 3) & 3)) * 8);     // swizzled source granule
    const int fr   = lane & 15;
    const int fks  = (((lane >> 4) ^ ((lane >> 1) & 3)) * 8);    // swizzled read granule

    for (int k0 = 0; k0 < K; k0 += BK) {
        __syncthreads();
        #pragma unroll
        for (int u = 0; u < 2; ++u) {
            int cchunk = wave * 2 + u;
            int r = cchunk * 16 + srow;
            GLOAD_LDS16(A  + (size_t)(row0 + r) * K + k0 + skk, &Als[cchunk * 512]);
            GLOAD_LDS16(Wt + (size_t)(col0 + r) * K + k0 + skk, &Bls[cchunk * 512]);
        }
        __syncthreads();

        bf16x8 af[4], bfr[4];
        #pragma unroll
        for (int i = 0; i < 4; ++i) {
            af[i]  = *(const bf16x8*)&Als[(wm + i * 16 + fr) * BK + fks];
            bfr[i] = *(const bf16x8*)&Bls[(wn + i * 16 + fr) * BK + fks];
        }
        #pragma unroll
        for (int mi = 0; mi < 4; ++mi)
            #pragma unroll
            for (int ni = 0; ni < 4; ++ni)
                acc[mi][ni] = __builtin_amdgcn_mfma_f32_16x16x32_bf16(af[mi], bfr[ni], acc[mi][ni], 0, 0, 0);
    }

    const int ccol  = lane & 15;
    const int crow4 = (lane >> 4) * 4;
    if (!isg) {
        #pragma unroll
        for (int mi = 0; mi < 4; ++mi) {
            #pragma unroll
            for (int ni = 0; ni < 4; ++ni) {
                int col = col0 + wn + ni * 16 + ccol;
                float bv = b_qkv[col];
                #pragma unroll
                for (int r = 0; r < 4; ++r) {
                    int row = row0 + wm + mi * 16 + crow4 + r;
                    qkvb[(size_t)row * (3 * D) + col] = to_bf16(acc[mi][ni][r] + bv);
                }
            }
        }
    } else {
        #pragma unroll
        for (int mi = 0; mi < 4; ++mi) {
            #pragma unroll
            for (int r = 0; r < 4; ++r) {
                int lrow = wm + mi * 16 + crow4 + r;
                float psum = 0.0f;
                #pragma unroll
                for (int ni = 0; ni < 4; ++ni) {
                    int col = col0 + wn + ni * 16 + ccol - 3 * D;   // [0,D)
                    float v = acc[mi][ni][r] + b_gate[col];
                    float sv = 1.0f / (1.0f + __expf(-v));
                    sigb[(size_t)(row0 + lrow) * D + col] = to_bf16(sv);
                    psum += sv;
                }
                atomicAdd(&gsum[lrow], psum);
            }
        }
        __syncthreads();
        if (tid < 128) atomicAdd(&gmean[row0 + tid], gsum[tid]);
    }
}

// ---------------------------------------------------------------------------
// Per-chunk state with INLINE gating on k: Sc[m][d] = sum_t Vt[m]*Kg[t][d],
// zc[d] = sum_t Kg[t][d], where Kg = elu1(k * sig/(mean+eps)).
// ---------------------------------------------------------------------------
__global__ __launch_bounds__(256) void chunk_state_mfma(const short* __restrict__ qkvb,
                                                        const short* __restrict__ sigb,
                                                        const float* __restrict__ gmean,
                                                        float* __restrict__ Sc,
                                                        float* __restrict__ zc) {
    __shared__ short Kt[DH * LS];   // [d][t] gated k
    __shared__ short Vt[DH * LS];   // [m][t]
    int idx = blockIdx.x;
    int c = idx & (NC - 1), h = (idx >> 5) & (H - 1), b = idx >> 9;
    size_t bt0 = (size_t)b * T + c * CHUNK;
    const short* kbase = qkvb + bt0 * (3 * D) + D + h * DH;
    const short* vbase = kbase + D;
    const short* sbase = sigb + bt0 * D + h * DH;
    int tid = threadIdx.x;

    #pragma unroll
    for (int l = 0; l < 2; ++l) {
        int i  = tid + l * 256;
        int t  = i >> 3;
        int d8 = (i & 7) * 8;
        float invm = 1.0f / (gmean[bt0 + t] * (1.0f / D) + 1e-5f);
        bf16x8 kv = *(const bf16x8*)(kbase + (size_t)t * (3 * D) + d8);
        bf16x8 vv = *(const bf16x8*)(vbase + (size_t)t * (3 * D) + d8);
        bf16x8 sg = *(const bf16x8*)(sbase + (size_t)t * D + d8);
        #pragma unroll
        for (int j = 0; j < 8; ++j) {
            float gn = bf2f(sg[j]) * invm;
            Kt[(d8 + j) * LS + t] = to_bf16(elu1(bf2f(kv[j]) * gn));
            Vt[(d8 + j) * LS + t] = vv[j];
        }
    }
    __syncthreads();

    const int wv = tid >> 6, lane = tid & 63;
    const int fr = lane & 15, quad = lane >> 4;
    const int fk = quad * 8, crow4 = quad * 4, ccol = lane & 15;
    const int mbase = wv * 16;

    bf16x8 af[2];
    af[0] = *(const bf16x8*)&Vt[(mbase + fr) * LS + fk];
    af[1] = *(const bf16x8*)&Vt[(mbase + fr) * LS + 32 + fk];

    f32x4 acc[4] = {};
    #pragma unroll
    for (int n = 0; n < 4; ++n) {
        #pragma unroll
        for (int ck = 0; ck < 2; ++ck) {
            bf16x8 bk = *(const bf16x8*)&Kt[(n * 16 + fr) * LS + ck * 32 + fk];
            acc[n] = __builtin_amdgcn_mfma_f32_16x16x32_bf16(af[ck], bk, acc[n], 0, 0, 0);
        }
    }

    float* Sd = Sc + (size_t)idx * (DH * DH);
    #pragma unroll
    for (int n = 0; n < 4; ++n)
        #pragma unroll
        for (int r = 0; r < 4; ++r)
            Sd[(mbase + crow4 + r) * DH + n * 16 + ccol] = acc[n][r];

    if (tid < DH) {
        float zs = 0.0f;
        for (int t = 0; t < CHUNK; ++t) zs += bf2f(Kt[tid * LS + t]);
        zc[(size_t)idx * DH + tid] = zs;
    }
}

// ---------------------------------------------------------------------------
// Exclusive prefix over chunks. Reads fp32 Sc, writes bf16 Spb; z in place.
// ---------------------------------------------------------------------------
__global__ __launch_bounds__(256) void chunk_prefix_kernel(const float* __restrict__ S,
                                                           short* __restrict__ Spb,
                                                           float* __restrict__ z) {
    int bh   = blockIdx.x >> 4;
    int part = blockIdx.x & 15;
    int e    = part * 256 + threadIdx.x;
    const float* Sb = S + (size_t)bh * NC * DH * DH;
    short* Pb = Spb + (size_t)bh * NC * DH * DH;
    float acc = 0.0f;
    for (int c = 0; c < NC; ++c) {
        size_t off = (size_t)c * DH * DH + e;
        float t = Sb[off];
        Pb[off] = to_bf16(acc);
        acc += t;
    }
    if (part == 0 && threadIdx.x < DH) {
        float* zb = z + (size_t)bh * NC * DH;
        float za = 0.0f;
        for (int c = 0; c < NC; ++c) {
            float* p = zb + c * DH + threadIdx.x;
            float t = *p; *p = za; za += t;
        }
    }
}

// ---------------------------------------------------------------------------
// Chunk attention with INLINE gating on q,k. Reads bf16 Sp. Writes bf16 out.
// ---------------------------------------------------------------------------
__global__ __launch_bounds__(256) void chunk_attn_mfma(const short* __restrict__ qkvb,
                                                       const short* __restrict__ sigb,
                                                       const float* __restrict__ gmean,
                                                       const short* __restrict__ Spb,
                                                       const float* __restrict__ zc,
                                                       short* __restrict__ attnb) {
    __shared__ short Qs[CHUNK * LS];   // [t][d] gated q
    __shared__ short Ks[CHUNK * LS];   // [s][d] gated k
    __shared__ short Vt[DH * LS];      // [m][s]
    __shared__ short Ss[DH * LS];      // [m][d]  (prefix state, bf16)
    __shared__ short As[CHUNK * LS];   // [t][s]
    __shared__ float zpL[DH];
    __shared__ float den[CHUNK];

    int idx = blockIdx.x;
    int c = idx & (NC - 1), h = (idx >> 5) & (H - 1), b = idx >> 9;
    size_t bt0 = (size_t)b * T + c * CHUNK;
    const short* qbase = qkvb + bt0 * (3 * D) + h * DH;
    const short* kbase = qbase + D;
    const short* vbase = qbase + 2 * D;
    const short* sbase = sigb + bt0 * D + h * DH;
    const short* spb = Spb + (size_t)idx * (DH * DH);
    int tid = threadIdx.x;

    #pragma unroll
    for (int l = 0; l < 2; ++l) {
        int i  = tid + l * 256;
        int t  = i >> 3;
        int d8 = (i & 7) * 8;
        float invm = 1.0f / (gmean[bt0 + t] * (1.0f / D) + 1e-5f);
        bf16x8 qv = *(const bf16x8*)(qbase + (size_t)t * (3 * D) + d8);
        bf16x8 kv = *(const bf16x8*)(kbase + (size_t)t * (3 * D) + d8);
        bf16x8 vv = *(const bf16x8*)(vbase + (size_t)t * (3 * D) + d8);
        bf16x8 sg = *(const bf16x8*)(sbase + (size_t)t * D + d8);
        bf16x8 qg, kg;
        #pragma unroll
        for (int j = 0; j < 8; ++j) {
            float gn = bf2f(sg[j]) * invm;
            qg[j] = to_bf16(elu1(bf2f(qv[j]) * gn));
            kg[j] = to_bf16(elu1(bf2f(kv[j]) * gn));
            Vt[(d8 + j) * LS + t] = vv[j];
        }
        *(bf16x8*)&Qs[t * LS + d8] = qg;
        *(bf16x8*)&Ks[t * LS + d8] = kg;
        *(bf16x8*)&Ss[t * LS + d8] = *(const bf16x8*)(spb + (size_t)i * 8);
    }
    if (tid < DH) zpL[tid] = zc[(size_t)idx * DH + tid];
    __syncthreads();

    const int wv = tid >> 6, lane = tid & 63;
    const int fr = lane & 15, quad = lane >> 4;
    const int fk = quad * 8, crow4 = quad * 4, ccol = lane & 15;
    const int tbase = wv * 16;

    bf16x8 aq[2];
    aq[0] = *(const bf16x8*)&Qs[(tbase + fr) * LS + fk];
    aq[1] = *(const bf16x8*)&Qs[(tbase + fr) * LS + 32 + fk];

    // scores C[t][s] = q_t . k_s
    f32x4 accs[4] = {};
    #pragma unroll
    for (int n = 0; n < 4; ++n) {
        #pragma unroll
        for (int ck = 0; ck < 2; ++ck) {
            bf16x8 bk = *(const bf16x8*)&Ks[(n * 16 + fr) * LS + ck * 32 + fk];
            accs[n] = __builtin_amdgcn_mfma_f32_16x16x32_bf16(aq[ck], bk, accs[n], 0, 0, 0);
        }
    }

    float part[4] = {0.f, 0.f, 0.f, 0.f};
    #pragma unroll
    for (int n = 0; n < 4; ++n) {
        #pragma unroll
        for (int r = 0; r < 4; ++r) {
            int tt = tbase + crow4 + r;
            int ss = n * 16 + ccol;
            float v = (ss <= tt) ? accs[n][r] : 0.0f;
            part[r] += v;
            As[tt * LS + ss] = to_bf16(v);
        }
    }
    #pragma unroll
    for (int r = 0; r < 4; ++r) {
        part[r] += __shfl_xor(part[r], 1, 64);
        part[r] += __shfl_xor(part[r], 2, 64);
        part[r] += __shfl_xor(part[r], 4, 64);
        part[r] += __shfl_xor(part[r], 8, 64);
    }
    if (fr == 0) {
        #pragma unroll
        for (int r = 0; r < 4; ++r) den[tbase + crow4 + r] = part[r];
    }
    __syncthreads();

    if (tid < CHUNK) {
        float qz = 0.0f;
        #pragma unroll 8
        for (int d = 0; d < DH; ++d) qz += bf2f(Qs[tid * LS + d]) * zpL[d];
        den[tid] += qz + 1e-5f;
    }

    // out C[t][m] = Q @ Sp + A @ V
    f32x4 acco[4] = {};
    #pragma unroll
    for (int m4 = 0; m4 < 4; ++m4) {
        #pragma unroll
        for (int ck = 0; ck < 2; ++ck) {
            bf16x8 bs = *(const bf16x8*)&Ss[(m4 * 16 + fr) * LS + ck * 32 + fk];
            acco[m4] = __builtin_amdgcn_mfma_f32_16x16x32_bf16(aq[ck], bs, acco[m4], 0, 0, 0);
        }
    }
    bf16x8 aa[2];
    aa[0] = *(const bf16x8*)&As[(tbase + fr) * LS + fk];
    aa[1] = *(const bf16x8*)&As[(tbase + fr) * LS + 32 + fk];
    #pragma unroll
    for (int m4 = 0; m4 < 4; ++m4) {
        #pragma unroll
        for (int ck = 0; ck < 2; ++ck) {
            bf16x8 bv = *(const bf16x8*)&Vt[(m4 * 16 + fr) * LS + ck * 32 + fk];
            acco[m4] = __builtin_amdgcn_mfma_f32_16x16x32_bf16(aa[ck], bv, acco[m4], 0, 0, 0);
        }
    }
    __syncthreads();

    short* obase = attnb + bt0 * D + h * DH;
    #pragma unroll
    for (int r = 0; r < 4; ++r) {
        int tt = tbase + crow4 + r;
        float rv = 1.0f / den[tt];
        #pragma unroll
        for (int m4 = 0; m4 < 4; ++m4)
            obase[(size_t)tt * D + m4 * 16 + ccol] = to_bf16(acco[m4][r] * rv);
    }
}

// ---------------------------------------------------------------------------
// Proj GEMM, BK=32 + swizzle: C[4096][1024] fp32 = A @ Bt^T + bias. 64x128 tile.
// ---------------------------------------------------------------------------
__global__ __launch_bounds__(256) void gemm_proj64(const short* __restrict__ A,
                                                   const short* __restrict__ Bt,
                                                   const float* __restrict__ bias,
                                                   float* __restrict__ C) {
    constexpr int BK = 32, K = 1024, N = 1024;
    __shared__ short Als[64 * BK];    // 4 KB
    __shared__ short Bls[128 * BK];   // 8 KB

    const int tid  = threadIdx.x;
    const int wave = tid >> 6;
    const int lane = tid & 63;
    const int row0 = blockIdx.y * 64;
    const int col0 = blockIdx.x * 128;
    const int wn = wave * 32;

    f32x4 acc[4][2] = {};
    const int srow = lane >> 2;
    const int skk  = (((lane & 3) ^ ((lane >> 3) & 3)) * 8);
    const int fr   = lane & 15;
    const int fks  = (((lane >> 4) ^ ((lane >> 1) & 3)) * 8);

    for (int k0 = 0; k0 < K; k0 += BK) {
        __syncthreads();
        #pragma unroll
        for (int u = 0; u < 3; ++u) {
            int cc = wave * 3 + u;   // 0..11; 0..3 -> A chunks, 4..11 -> B chunks
            if (cc < 4) {
                int r = cc * 16 + srow;
                GLOAD_LDS16(A + (size_t)(row0 + r) * K + k0 + skk, &Als[cc * 512]);
            } else {
                int c2 = cc - 4;
                int r = c2 * 16 + srow;
                GLOAD_LDS16(Bt + (size_t)(col0 + r) * K + k0 + skk, &Bls[c2 * 512]);
            }
        }
        __syncthreads();

        bf16x8 af[4], bfr[2];
        #pragma unroll
        for (int i = 0; i < 4; ++i)
            af[i] = *(const bf16x8*)&Als[(i * 16 + fr) * BK + fks];
        #pragma unroll
        for (int j = 0; j < 2; ++j)
            bfr[j] = *(const bf16x8*)&Bls[(wn + j * 16 + fr) * BK + fks];
        #pragma unroll
        for (int mi = 0; mi < 4; ++mi)
            #pragma unroll
            for (int ni = 0; ni < 2; ++ni)
                acc[mi][ni] = __builtin_amdgcn_mfma_f32_16x16x32_bf16(af[mi], bfr[ni], acc[mi][ni], 0, 0, 0);
    }

    const int ccol  = lane & 15;
    const int crow4 = (lane >> 4) * 4;
    #pragma unroll
    for (int mi = 0; mi < 4; ++mi) {
        #pragma unroll
        for (int ni = 0; ni < 2; ++ni) {
            int col = col0 + wn + ni * 16 + ccol;
            float bv = bias[col];
            #pragma unroll
            for (int r = 0; r < 4; ++r) {
                int row = row0 + mi * 16 + crow4 + r;
                C[(size_t)row * N + col] = acc[mi][ni][r] + bv;
            }
        }
    }
}

// ---------------------------------------------------------------------------
extern "C" void kernel_launch(void* const* d_in, const int* in_sizes, int n_in,
                              void* d_out, int out_size, void* d_ws, size_t ws_size,
                              hipStream_t stream) {
    const float* x      = (const float*)d_in[0];
    const float* ln_g   = (const float*)d_in[1];
    const float* ln_b   = (const float*)d_in[2];
    const float* w_qkv  = (const float*)d_in[3];
    const float* b_qkv  = (const float*)d_in[4];
    const float* w_gate = (const float*)d_in[5];
    const float* b_gate = (const float*)d_in[6];
    const float* w_proj = (const float*)d_in[7];
    const float* b_proj = (const float*)d_in[8];
    float* out = (float*)d_out;

    short* xnb   = (short*)d_ws;                       // BT*D bf16 (8 MB)  [dead after GEMM]
    short* xb    = xnb + (size_t)BT * D;               // BT*D bf16 (8 MB)  [dead after GEMM]
    short* wTc   = xb + (size_t)BT * D;                // 4096*1024 bf16 (8 MB) [dead after GEMM]
    short* wTp   = wTc + (size_t)4096 * 1024;          // D*D bf16 (2 MB)
    short* qkvb  = wTp + (size_t)D * D;                // BT*3D bf16 (24 MB)
    short* sigb  = qkvb + (size_t)BT * 3 * D;          // BT*D bf16 (8 MB)
    short* attnb = sigb + (size_t)BT * D;              // BT*D bf16 (8 MB)
    float* zc    = (float*)(attnb + (size_t)BT * D);   // Bb*H*NC*DH fp32 (256 KB)
    float* gmean = zc + (size_t)Bb * H * NC * DH;      // BT fp32 (16 KB)
    float* Sc    = (float*)xnb;                        // Bb*H*NC*DH*DH fp32 (16 MB), aliases xnb+xb
    short* Spb   = wTc;                                // BT*D bf16 (8 MB), aliases wTc

    pre_kernel<<<BT + 5120, 256, 0, stream>>>(x, ln_g, ln_b, w_qkv, w_gate, w_proj,
                                              xnb, xb, wTc, wTp, gmean);
    gemm_fused_qkvgate<<<dim3(32, 32), 256, 0, stream>>>(
        xnb, xb, wTc, b_qkv, b_gate, qkvb, sigb, gmean);
    chunk_state_mfma<<<Bb * H * NC, 256, 0, stream>>>(qkvb, sigb, gmean, Sc, zc);
    chunk_prefix_kernel<<<Bb * H * 16, 256, 0, stream>>>(Sc, Spb, zc);
    chunk_attn_mfma<<<Bb * H * NC, 256, 0, stream>>>(qkvb, sigb, gmean, Spb, zc, attnb);
    gemm_proj64<<<dim3(D / 128, BT / 64), 256, 0, stream>>>(attnb, wTp, b_proj, out);
}

// Round 7
// 211.094 us; speedup vs baseline: 1.1752x; 1.0563x over previous
//
#include <hip/hip_runtime.h>
#include <math.h>

// Problem constants
constexpr int D      = 1024;
constexpr int H      = 16;
constexpr int DH     = 64;
constexpr int Bb     = 2;
constexpr int T      = 2048;
constexpr int BT     = Bb * T;       // 4096
constexpr int CHUNK  = 64;
constexpr int NC     = T / CHUNK;    // 32
constexpr int LS     = 72;           // LDS row stride (shorts) for chunk kernels

typedef __attribute__((ext_vector_type(8))) short bf16x8;
typedef __attribute__((ext_vector_type(4))) float f32x4;

#define GLOAD_LDS16(gp, lp) \
    __builtin_amdgcn_global_load_lds((const __attribute__((address_space(1))) void*)(gp), \
                                     (__attribute__((address_space(3))) void*)(lp), 16, 0, 0)

__device__ __forceinline__ short to_bf16(float f) {
    unsigned u = __float_as_uint(f);
    unsigned r = (u + 0x7fffu + ((u >> 16) & 1u)) >> 16;
    return (short)r;
}
__device__ __forceinline__ float bf2f(short s) {
    return __uint_as_float(((unsigned)(unsigned short)s) << 16);
}

__device__ __forceinline__ float block_sum_256(float v, float* sbuf) {
    #pragma unroll
    for (int off = 32; off > 0; off >>= 1) v += __shfl_down(v, off, 64);
    int lane = threadIdx.x & 63;
    int wid  = threadIdx.x >> 6;
    if (lane == 0) sbuf[wid] = v;
    __syncthreads();
    float r = (threadIdx.x < 4) ? sbuf[threadIdx.x] : 0.0f;
    r += __shfl_down(r, 2, 64);
    r += __shfl_down(r, 1, 64);
    if (threadIdx.x == 0) sbuf[0] = r;
    __syncthreads();
    float outv = sbuf[0];
    __syncthreads();
    return outv;
}

__device__ __forceinline__ float elu1(float x) {
    return x > 0.0f ? x + 1.0f : __expf(x);
}

// ---------------------------------------------------------------------------
// Merged prologue: blocks [0,BT): LayerNorm + zero gmean[row];
// [BT, BT+5120): three weight transposes (fp32 -> bf16, [K,N] -> [N,K]).
// ---------------------------------------------------------------------------
__global__ __launch_bounds__(256) void pre_kernel(const float* __restrict__ x,
                                                  const float* __restrict__ g,
                                                  const float* __restrict__ b,
                                                  const float* __restrict__ wq,
                                                  const float* __restrict__ wg,
                                                  const float* __restrict__ wp,
                                                  short* __restrict__ ynb,
                                                  short* __restrict__ xbb,
                                                  short* __restrict__ wTcomb,
                                                  short* __restrict__ wTp,
                                                  float* __restrict__ gmean) {
    __shared__ float sbuf[4];
    __shared__ short tile[32][33];
    int bid = blockIdx.x;
    if (bid < BT) {
        int row = bid;
        if (threadIdx.x == 0) gmean[row] = 0.0f;
        const float* xr = x + (size_t)row * D;
        int c = threadIdx.x * 4;
        float4 xv = *(const float4*)(xr + c);
        float mu = block_sum_256(xv.x + xv.y + xv.z + xv.w, sbuf) * (1.0f / D);
        float d0 = xv.x - mu, d1 = xv.y - mu, d2 = xv.z - mu, d3 = xv.w - mu;
        float var = block_sum_256(d0*d0 + d1*d1 + d2*d2 + d3*d3, sbuf) * (1.0f / D);
        float rstd = rsqrtf(var + 1e-5f);
        float4 gv = *(const float4*)(g + c);
        float4 bv = *(const float4*)(b + c);
        short4 o, xo;
        o.x = to_bf16(d0 * rstd * gv.x + bv.x);
        o.y = to_bf16(d1 * rstd * gv.y + bv.y);
        o.z = to_bf16(d2 * rstd * gv.z + bv.z);
        o.w = to_bf16(d3 * rstd * gv.w + bv.w);
        xo.x = to_bf16(xv.x); xo.y = to_bf16(xv.y);
        xo.z = to_bf16(xv.z); xo.w = to_bf16(xv.w);
        *(short4*)(ynb + (size_t)row * D + c) = o;
        *(short4*)(xbb + (size_t)row * D + c) = xo;
    } else {
        int t2 = bid - BT;
        const float* W; short* Wt; int N; int t;
        if (t2 < 3072)      { W = wq; Wt = wTcomb;                       N = 3072; t = t2; }
        else if (t2 < 4096) { W = wg; Wt = wTcomb + (size_t)3072 * 1024; N = 1024; t = t2 - 3072; }
        else                { W = wp; Wt = wTp;                          N = 1024; t = t2 - 4096; }
        int ntiles = N >> 5;
        int nb = (t % ntiles) * 32, kb = (t / ntiles) * 32;
        int tx = threadIdx.x & 31, ty = threadIdx.x >> 5;
        #pragma unroll
        for (int i = 0; i < 4; ++i) {
            int k = kb + ty + i * 8;
            tile[ty + i * 8][tx] = to_bf16(W[(size_t)k * N + nb + tx]);
        }
        __syncthreads();
        #pragma unroll
        for (int i = 0; i < 4; ++i) {
            int n = nb + ty + i * 8;
            Wt[(size_t)n * 1024 + kb + tx] = tile[tx][ty + i * 8];
        }
    }
}

// ---------------------------------------------------------------------------
// Combined qkv+gate GEMM, BK=32, R4 (un-swizzled) LDS path.
// cols [0,3D): qkv from x_norm -> bf16 qkvb.
// cols [3D,4D): gate from raw x -> sigmoid -> bf16 sigb; per-row sigmoid sums
// reduced within each quad then one global atomicAdd into gmean.
// ---------------------------------------------------------------------------
__global__ __launch_bounds__(256) void gemm_fused_qkvgate(const short* __restrict__ xnb,
                                                          const short* __restrict__ xb,
                                                          const short* __restrict__ Wt,
                                                          const float* __restrict__ b_qkv,
                                                          const float* __restrict__ b_gate,
                                                          short* __restrict__ qkvb,
                                                          short* __restrict__ sigb,
                                                          float* __restrict__ gmean) {
    constexpr int BK = 32, K = 1024;
    __shared__ short Als[128 * BK];   // 8 KB
    __shared__ short Bls[128 * BK];   // 8 KB

    const int tid  = threadIdx.x;
    const int wave = tid >> 6;
    const int lane = tid & 63;
    const int row0 = blockIdx.y * 128;
    const int col0 = blockIdx.x * 128;
    const bool isg = (col0 >= 3 * D);
    const short* A = isg ? xb : xnb;
    const int wm = (wave & 1) * 64;
    const int wn = (wave >> 1) * 64;

    f32x4 acc[4][4] = {};
    const int srow = lane >> 2;            // 0..15
    const int skk  = (lane & 3) * 8;       // 0,8,16,24
    const int fr = lane & 15;
    const int fk = (lane >> 4) * 8;

    for (int k0 = 0; k0 < K; k0 += BK) {
        __syncthreads();
        #pragma unroll
        for (int u = 0; u < 2; ++u) {
            int cchunk = wave * 2 + u;
            int r = cchunk * 16 + srow;
            GLOAD_LDS16(A  + (size_t)(row0 + r) * K + k0 + skk, &Als[cchunk * 512]);
            GLOAD_LDS16(Wt + (size_t)(col0 + r) * K + k0 + skk, &Bls[cchunk * 512]);
        }
        __syncthreads();

        bf16x8 af[4], bfr[4];
        #pragma unroll
        for (int i = 0; i < 4; ++i) {
            af[i]  = *(const bf16x8*)&Als[(wm + i * 16 + fr) * BK + fk];
            bfr[i] = *(const bf16x8*)&Bls[(wn + i * 16 + fr) * BK + fk];
        }
        #pragma unroll
        for (int mi = 0; mi < 4; ++mi)
            #pragma unroll
            for (int ni = 0; ni < 4; ++ni)
                acc[mi][ni] = __builtin_amdgcn_mfma_f32_16x16x32_bf16(af[mi], bfr[ni], acc[mi][ni], 0, 0, 0);
    }

    const int ccol  = lane & 15;
    const int crow4 = (lane >> 4) * 4;
    if (!isg) {
        #pragma unroll
        for (int mi = 0; mi < 4; ++mi) {
            #pragma unroll
            for (int ni = 0; ni < 4; ++ni) {
                int col = col0 + wn + ni * 16 + ccol;
                float bv = b_qkv[col];
                #pragma unroll
                for (int r = 0; r < 4; ++r) {
                    int row = row0 + wm + mi * 16 + crow4 + r;
                    qkvb[(size_t)row * (3 * D) + col] = to_bf16(acc[mi][ni][r] + bv);
                }
            }
        }
    } else {
        #pragma unroll
        for (int mi = 0; mi < 4; ++mi) {
            #pragma unroll
            for (int r = 0; r < 4; ++r) {
                int lrow = wm + mi * 16 + crow4 + r;
                float psum = 0.0f;
                #pragma unroll
                for (int ni = 0; ni < 4; ++ni) {
                    int col = col0 + wn + ni * 16 + ccol - 3 * D;   // [0,D)
                    float v = acc[mi][ni][r] + b_gate[col];
                    float sv = 1.0f / (1.0f + __expf(-v));
                    sigb[(size_t)(row0 + lrow) * D + col] = to_bf16(sv);
                    psum += sv;
                }
                // reduce over the 16 lanes of this quad (they share lrow)
                psum += __shfl_xor(psum, 1, 64);
                psum += __shfl_xor(psum, 2, 64);
                psum += __shfl_xor(psum, 4, 64);
                psum += __shfl_xor(psum, 8, 64);
                if (ccol == 0) atomicAdd(&gmean[row0 + lrow], psum);
            }
        }
    }
}

// ---------------------------------------------------------------------------
// Per-chunk state with INLINE gating on k: Sc[m][d] = sum_t Vt[m]*Kg[t][d],
// zc[d] = sum_t Kg[t][d], where Kg = elu1(k * sig/(mean+eps)).
// ---------------------------------------------------------------------------
__global__ __launch_bounds__(256) void chunk_state_mfma(const short* __restrict__ qkvb,
                                                        const short* __restrict__ sigb,
                                                        const float* __restrict__ gmean,
                                                        float* __restrict__ Sc,
                                                        float* __restrict__ zc) {
    __shared__ short Kt[DH * LS];   // [d][t] gated k
    __shared__ short Vt[DH * LS];   // [m][t]
    int idx = blockIdx.x;
    int c = idx & (NC - 1), h = (idx >> 5) & (H - 1), b = idx >> 9;
    size_t bt0 = (size_t)b * T + c * CHUNK;
    const short* kbase = qkvb + bt0 * (3 * D) + D + h * DH;
    const short* vbase = kbase + D;
    const short* sbase = sigb + bt0 * D + h * DH;
    int tid = threadIdx.x;

    #pragma unroll
    for (int l = 0; l < 2; ++l) {
        int i  = tid + l * 256;
        int t  = i >> 3;
        int d8 = (i & 7) * 8;
        float invm = 1.0f / (gmean[bt0 + t] * (1.0f / D) + 1e-5f);
        bf16x8 kv = *(const bf16x8*)(kbase + (size_t)t * (3 * D) + d8);
        bf16x8 vv = *(const bf16x8*)(vbase + (size_t)t * (3 * D) + d8);
        bf16x8 sg = *(const bf16x8*)(sbase + (size_t)t * D + d8);
        #pragma unroll
        for (int j = 0; j < 8; ++j) {
            float gn = bf2f(sg[j]) * invm;
            Kt[(d8 + j) * LS + t] = to_bf16(elu1(bf2f(kv[j]) * gn));
            Vt[(d8 + j) * LS + t] = vv[j];
        }
    }
    __syncthreads();

    const int wv = tid >> 6, lane = tid & 63;
    const int fr = lane & 15, quad = lane >> 4;
    const int fk = quad * 8, crow4 = quad * 4, ccol = lane & 15;
    const int mbase = wv * 16;

    bf16x8 af[2];
    af[0] = *(const bf16x8*)&Vt[(mbase + fr) * LS + fk];
    af[1] = *(const bf16x8*)&Vt[(mbase + fr) * LS + 32 + fk];

    f32x4 acc[4] = {};
    #pragma unroll
    for (int n = 0; n < 4; ++n) {
        #pragma unroll
        for (int ck = 0; ck < 2; ++ck) {
            bf16x8 bk = *(const bf16x8*)&Kt[(n * 16 + fr) * LS + ck * 32 + fk];
            acc[n] = __builtin_amdgcn_mfma_f32_16x16x32_bf16(af[ck], bk, acc[n], 0, 0, 0);
        }
    }

    float* Sd = Sc + (size_t)idx * (DH * DH);
    #pragma unroll
    for (int n = 0; n < 4; ++n)
        #pragma unroll
        for (int r = 0; r < 4; ++r)
            Sd[(mbase + crow4 + r) * DH + n * 16 + ccol] = acc[n][r];

    if (tid < DH) {
        float zs = 0.0f;
        for (int t = 0; t < CHUNK; ++t) zs += bf2f(Kt[tid * LS + t]);
        zc[(size_t)idx * DH + tid] = zs;
    }
}

// ---------------------------------------------------------------------------
// Exclusive prefix over chunks. Reads fp32 Sc, writes bf16 Spb; z in place.
// ---------------------------------------------------------------------------
__global__ __launch_bounds__(256) void chunk_prefix_kernel(const float* __restrict__ S,
                                                           short* __restrict__ Spb,
                                                           float* __restrict__ z) {
    int bh   = blockIdx.x >> 4;
    int part = blockIdx.x & 15;
    int e    = part * 256 + threadIdx.x;
    const float* Sb = S + (size_t)bh * NC * DH * DH;
    short* Pb = Spb + (size_t)bh * NC * DH * DH;
    float acc = 0.0f;
    for (int c = 0; c < NC; ++c) {
        size_t off = (size_t)c * DH * DH + e;
        float t = Sb[off];
        Pb[off] = to_bf16(acc);
        acc += t;
    }
    if (part == 0 && threadIdx.x < DH) {
        float* zb = z + (size_t)bh * NC * DH;
        float za = 0.0f;
        for (int c = 0; c < NC; ++c) {
            float* p = zb + c * DH + threadIdx.x;
            float t = *p; *p = za; za += t;
        }
    }
}

// ---------------------------------------------------------------------------
// Chunk attention with INLINE gating on q,k. Reads bf16 Sp. Writes bf16 out.
// ---------------------------------------------------------------------------
__global__ __launch_bounds__(256) void chunk_attn_mfma(const short* __restrict__ qkvb,
                                                       const short* __restrict__ sigb,
                                                       const float* __restrict__ gmean,
                                                       const short* __restrict__ Spb,
                                                       const float* __restrict__ zc,
                                                       short* __restrict__ attnb) {
    __shared__ short Qs[CHUNK * LS];   // [t][d] gated q
    __shared__ short Ks[CHUNK * LS];   // [s][d] gated k
    __shared__ short Vt[DH * LS];      // [m][s]
    __shared__ short Ss[DH * LS];      // [m][d]  (prefix state, bf16)
    __shared__ short As[CHUNK * LS];   // [t][s]
    __shared__ float zpL[DH];
    __shared__ float den[CHUNK];

    int idx = blockIdx.x;
    int c = idx & (NC - 1), h = (idx >> 5) & (H - 1), b = idx >> 9;
    size_t bt0 = (size_t)b * T + c * CHUNK;
    const short* qbase = qkvb + bt0 * (3 * D) + h * DH;
    const short* kbase = qbase + D;
    const short* vbase = qbase + 2 * D;
    const short* sbase = sigb + bt0 * D + h * DH;
    const short* spb = Spb + (size_t)idx * (DH * DH);
    int tid = threadIdx.x;

    #pragma unroll
    for (int l = 0; l < 2; ++l) {
        int i  = tid + l * 256;
        int t  = i >> 3;
        int d8 = (i & 7) * 8;
        float invm = 1.0f / (gmean[bt0 + t] * (1.0f / D) + 1e-5f);
        bf16x8 qv = *(const bf16x8*)(qbase + (size_t)t * (3 * D) + d8);
        bf16x8 kv = *(const bf16x8*)(kbase + (size_t)t * (3 * D) + d8);
        bf16x8 vv = *(const bf16x8*)(vbase + (size_t)t * (3 * D) + d8);
        bf16x8 sg = *(const bf16x8*)(sbase + (size_t)t * D + d8);
        bf16x8 qg, kg;
        #pragma unroll
        for (int j = 0; j < 8; ++j) {
            float gn = bf2f(sg[j]) * invm;
            qg[j] = to_bf16(elu1(bf2f(qv[j]) * gn));
            kg[j] = to_bf16(elu1(bf2f(kv[j]) * gn));
            Vt[(d8 + j) * LS + t] = vv[j];
        }
        *(bf16x8*)&Qs[t * LS + d8] = qg;
        *(bf16x8*)&Ks[t * LS + d8] = kg;
        *(bf16x8*)&Ss[t * LS + d8] = *(const bf16x8*)(spb + (size_t)i * 8);
    }
    if (tid < DH) zpL[tid] = zc[(size_t)idx * DH + tid];
    __syncthreads();

    const int wv = tid >> 6, lane = tid & 63;
    const int fr = lane & 15, quad = lane >> 4;
    const int fk = quad * 8, crow4 = quad * 4, ccol = lane & 15;
    const int tbase = wv * 16;

    bf16x8 aq[2];
    aq[0] = *(const bf16x8*)&Qs[(tbase + fr) * LS + fk];
    aq[1] = *(const bf16x8*)&Qs[(tbase + fr) * LS + 32 + fk];

    // scores C[t][s] = q_t . k_s
    f32x4 accs[4] = {};
    #pragma unroll
    for (int n = 0; n < 4; ++n) {
        #pragma unroll
        for (int ck = 0; ck < 2; ++ck) {
            bf16x8 bk = *(const bf16x8*)&Ks[(n * 16 + fr) * LS + ck * 32 + fk];
            accs[n] = __builtin_amdgcn_mfma_f32_16x16x32_bf16(aq[ck], bk, accs[n], 0, 0, 0);
        }
    }

    float part[4] = {0.f, 0.f, 0.f, 0.f};
    #pragma unroll
    for (int n = 0; n < 4; ++n) {
        #pragma unroll
        for (int r = 0; r < 4; ++r) {
            int tt = tbase + crow4 + r;
            int ss = n * 16 + ccol;
            float v = (ss <= tt) ? accs[n][r] : 0.0f;
            part[r] += v;
            As[tt * LS + ss] = to_bf16(v);
        }
    }
    #pragma unroll
    for (int r = 0; r < 4; ++r) {
        part[r] += __shfl_xor(part[r], 1, 64);
        part[r] += __shfl_xor(part[r], 2, 64);
        part[r] += __shfl_xor(part[r], 4, 64);
        part[r] += __shfl_xor(part[r], 8, 64);
    }
    if (fr == 0) {
        #pragma unroll
        for (int r = 0; r < 4; ++r) den[tbase + crow4 + r] = part[r];
    }
    __syncthreads();

    if (tid < CHUNK) {
        float qz = 0.0f;
        #pragma unroll 8
        for (int d = 0; d < DH; ++d) qz += bf2f(Qs[tid * LS + d]) * zpL[d];
        den[tid] += qz + 1e-5f;
    }

    // out C[t][m] = Q @ Sp + A @ V
    f32x4 acco[4] = {};
    #pragma unroll
    for (int m4 = 0; m4 < 4; ++m4) {
        #pragma unroll
        for (int ck = 0; ck < 2; ++ck) {
            bf16x8 bs = *(const bf16x8*)&Ss[(m4 * 16 + fr) * LS + ck * 32 + fk];
            acco[m4] = __builtin_amdgcn_mfma_f32_16x16x32_bf16(aq[ck], bs, acco[m4], 0, 0, 0);
        }
    }
    bf16x8 aa[2];
    aa[0] = *(const bf16x8*)&As[(tbase + fr) * LS + fk];
    aa[1] = *(const bf16x8*)&As[(tbase + fr) * LS + 32 + fk];
    #pragma unroll
    for (int m4 = 0; m4 < 4; ++m4) {
        #pragma unroll
        for (int ck = 0; ck < 2; ++ck) {
            bf16x8 bv = *(const bf16x8*)&Vt[(m4 * 16 + fr) * LS + ck * 32 + fk];
            acco[m4] = __builtin_amdgcn_mfma_f32_16x16x32_bf16(aa[ck], bv, acco[m4], 0, 0, 0);
        }
    }
    __syncthreads();

    short* obase = attnb + bt0 * D + h * DH;
    #pragma unroll
    for (int r = 0; r < 4; ++r) {
        int tt = tbase + crow4 + r;
        float rv = 1.0f / den[tt];
        #pragma unroll
        for (int m4 = 0; m4 < 4; ++m4)
            obase[(size_t)tt * D + m4 * 16 + ccol] = to_bf16(acco[m4][r] * rv);
    }
}

// ---------------------------------------------------------------------------
// Proj GEMM, BK=32, R4 (un-swizzled): C[4096][1024] fp32 = A @ Bt^T + bias.
// 64x128 tile, 512 blocks.
// ---------------------------------------------------------------------------
__global__ __launch_bounds__(256) void gemm_proj64(const short* __restrict__ A,
                                                   const short* __restrict__ Bt,
                                                   const float* __restrict__ bias,
                                                   float* __restrict__ C) {
    constexpr int BK = 32, K = 1024, N = 1024;
    __shared__ short Als[64 * BK];    // 4 KB
    __shared__ short Bls[128 * BK];   // 8 KB

    const int tid  = threadIdx.x;
    const int wave = tid >> 6;
    const int lane = tid & 63;
    const int row0 = blockIdx.y * 64;
    const int col0 = blockIdx.x * 128;
    const int wn = wave * 32;

    f32x4 acc[4][2] = {};
    const int srow = lane >> 2;
    const int skk  = (lane & 3) * 8;
    const int fr = lane & 15;
    const int fk = (lane >> 4) * 8;

    for (int k0 = 0; k0 < K; k0 += BK) {
        __syncthreads();
        #pragma unroll
        for (int u = 0; u < 3; ++u) {
            int cc = wave * 3 + u;   // 0..11; 0..3 -> A chunks, 4..11 -> B chunks
            if (cc < 4) {
                int r = cc * 16 + srow;
                GLOAD_LDS16(A + (size_t)(row0 + r) * K + k0 + skk, &Als[cc * 512]);
            } else {
                int c2 = cc - 4;
                int r = c2 * 16 + srow;
                GLOAD_LDS16(Bt + (size_t)(col0 + r) * K + k0 + skk, &Bls[c2 * 512]);
            }
        }
        __syncthreads();

        bf16x8 af[4], bfr[2];
        #pragma unroll
        for (int i = 0; i < 4; ++i)
            af[i] = *(const bf16x8*)&Als[(i * 16 + fr) * BK + fk];
        #pragma unroll
        for (int j = 0; j < 2; ++j)
            bfr[j] = *(const bf16x8*)&Bls[(wn + j * 16 + fr) * BK + fk];
        #pragma unroll
        for (int mi = 0; mi < 4; ++mi)
            #pragma unroll
            for (int ni = 0; ni < 2; ++ni)
                acc[mi][ni] = __builtin_amdgcn_mfma_f32_16x16x32_bf16(af[mi], bfr[ni], acc[mi][ni], 0, 0, 0);
    }

    const int ccol  = lane & 15;
    const int crow4 = (lane >> 4) * 4;
    #pragma unroll
    for (int mi = 0; mi < 4; ++mi) {
        #pragma unroll
        for (int ni = 0; ni < 2; ++ni) {
            int col = col0 + wn + ni * 16 + ccol;
            float bv = bias[col];
            #pragma unroll
            for (int r = 0; r < 4; ++r) {
                int row = row0 + mi * 16 + crow4 + r;
                C[(size_t)row * N + col] = acc[mi][ni][r] + bv;
            }
        }
    }
}

// ---------------------------------------------------------------------------
extern "C" void kernel_launch(void* const* d_in, const int* in_sizes, int n_in,
                              void* d_out, int out_size, void* d_ws, size_t ws_size,
                              hipStream_t stream) {
    const float* x      = (const float*)d_in[0];
    const float* ln_g   = (const float*)d_in[1];
    const float* ln_b   = (const float*)d_in[2];
    const float* w_qkv  = (const float*)d_in[3];
    const float* b_qkv  = (const float*)d_in[4];
    const float* w_gate = (const float*)d_in[5];
    const float* b_gate = (const float*)d_in[6];
    const float* w_proj = (const float*)d_in[7];
    const float* b_proj = (const float*)d_in[8];
    float* out = (float*)d_out;

    short* xnb   = (short*)d_ws;                       // BT*D bf16 (8 MB)  [dead after GEMM]
    short* xb    = xnb + (size_t)BT * D;               // BT*D bf16 (8 MB)  [dead after GEMM]
    short* wTc   = xb + (size_t)BT * D;                // 4096*1024 bf16 (8 MB) [dead after GEMM]
    short* wTp   = wTc + (size_t)4096 * 1024;          // D*D bf16 (2 MB)
    short* qkvb  = wTp + (size_t)D * D;                // BT*3D bf16 (24 MB)
    short* sigb  = qkvb + (size_t)BT * 3 * D;          // BT*D bf16 (8 MB)
    short* attnb = sigb + (size_t)BT * D;              // BT*D bf16 (8 MB)
    float* zc    = (float*)(attnb + (size_t)BT * D);   // Bb*H*NC*DH fp32 (256 KB)
    float* gmean = zc + (size_t)Bb * H * NC * DH;      // BT fp32 (16 KB)
    float* Sc    = (float*)xnb;                        // Bb*H*NC*DH*DH fp32 (16 MB), aliases xnb+xb
    short* Spb   = wTc;                                // BT*D bf16 (8 MB), aliases wTc

    pre_kernel<<<BT + 5120, 256, 0, stream>>>(x, ln_g, ln_b, w_qkv, w_gate, w_proj,
                                              xnb, xb, wTc, wTp, gmean);
    gemm_fused_qkvgate<<<dim3(32, 32), 256, 0, stream>>>(
        xnb, xb, wTc, b_qkv, b_gate, qkvb, sigb, gmean);
    chunk_state_mfma<<<Bb * H * NC, 256, 0, stream>>>(qkvb, sigb, gmean, Sc, zc);
    chunk_prefix_kernel<<<Bb * H * 16, 256, 0, stream>>>(Sc, Spb, zc);
    chunk_attn_mfma<<<Bb * H * NC, 256, 0, stream>>>(qkvb, sigb, gmean, Spb, zc, attnb);
    gemm_proj64<<<dim3(D / 128, BT / 64), 256, 0, stream>>>(attnb, wTp, b_proj, out);
}

// Round 8
// 205.689 us; speedup vs baseline: 1.2061x; 1.0263x over previous
//
#include <hip/hip_runtime.h>
#include <math.h>

// Problem constants
constexpr int D      = 1024;
constexpr int H      = 16;
constexpr int DH     = 64;
constexpr int Bb     = 2;
constexpr int T      = 2048;
constexpr int BT     = Bb * T;       // 4096
constexpr int CHUNK  = 64;
constexpr int NC     = T / CHUNK;    // 32
constexpr int LS     = 72;           // LDS row stride (shorts) for chunk kernels

typedef __attribute__((ext_vector_type(8))) short bf16x8;
typedef __attribute__((ext_vector_type(4))) float f32x4;

#define GLOAD_LDS16(gp, lp) \
    __builtin_amdgcn_global_load_lds((const __attribute__((address_space(1))) void*)(gp), \
                                     (__attribute__((address_space(3))) void*)(lp), 16, 0, 0)

__device__ __forceinline__ short to_bf16(float f) {
    unsigned u = __float_as_uint(f);
    unsigned r = (u + 0x7fffu + ((u >> 16) & 1u)) >> 16;
    return (short)r;
}
__device__ __forceinline__ float bf2f(short s) {
    return __uint_as_float(((unsigned)(unsigned short)s) << 16);
}

__device__ __forceinline__ float block_sum_256(float v, float* sbuf) {
    #pragma unroll
    for (int off = 32; off > 0; off >>= 1) v += __shfl_down(v, off, 64);
    int lane = threadIdx.x & 63;
    int wid  = threadIdx.x >> 6;
    if (lane == 0) sbuf[wid] = v;
    __syncthreads();
    float r = (threadIdx.x < 4) ? sbuf[threadIdx.x] : 0.0f;
    r += __shfl_down(r, 2, 64);
    r += __shfl_down(r, 1, 64);
    if (threadIdx.x == 0) sbuf[0] = r;
    __syncthreads();
    float outv = sbuf[0];
    __syncthreads();
    return outv;
}

__device__ __forceinline__ float elu1(float x) {
    return x > 0.0f ? x + 1.0f : __expf(x);
}

// ---------------------------------------------------------------------------
// Merged prologue: blocks [0,BT): LayerNorm + zero gmean[row];
// [BT, BT+5120): three weight transposes (fp32 -> bf16, [K,N] -> [N,K]).
// ---------------------------------------------------------------------------
__global__ __launch_bounds__(256) void pre_kernel(const float* __restrict__ x,
                                                  const float* __restrict__ g,
                                                  const float* __restrict__ b,
                                                  const float* __restrict__ wq,
                                                  const float* __restrict__ wg,
                                                  const float* __restrict__ wp,
                                                  short* __restrict__ ynb,
                                                  short* __restrict__ xbb,
                                                  short* __restrict__ wTcomb,
                                                  short* __restrict__ wTp,
                                                  float* __restrict__ gmean) {
    __shared__ float sbuf[4];
    __shared__ short tile[32][33];
    int bid = blockIdx.x;
    if (bid < BT) {
        int row = bid;
        if (threadIdx.x == 0) gmean[row] = 0.0f;
        const float* xr = x + (size_t)row * D;
        int c = threadIdx.x * 4;
        float4 xv = *(const float4*)(xr + c);
        float mu = block_sum_256(xv.x + xv.y + xv.z + xv.w, sbuf) * (1.0f / D);
        float d0 = xv.x - mu, d1 = xv.y - mu, d2 = xv.z - mu, d3 = xv.w - mu;
        float var = block_sum_256(d0*d0 + d1*d1 + d2*d2 + d3*d3, sbuf) * (1.0f / D);
        float rstd = rsqrtf(var + 1e-5f);
        float4 gv = *(const float4*)(g + c);
        float4 bv = *(const float4*)(b + c);
        short4 o, xo;
        o.x = to_bf16(d0 * rstd * gv.x + bv.x);
        o.y = to_bf16(d1 * rstd * gv.y + bv.y);
        o.z = to_bf16(d2 * rstd * gv.z + bv.z);
        o.w = to_bf16(d3 * rstd * gv.w + bv.w);
        xo.x = to_bf16(xv.x); xo.y = to_bf16(xv.y);
        xo.z = to_bf16(xv.z); xo.w = to_bf16(xv.w);
        *(short4*)(ynb + (size_t)row * D + c) = o;
        *(short4*)(xbb + (size_t)row * D + c) = xo;
    } else {
        int t2 = bid - BT;
        const float* W; short* Wt; int N; int t;
        if (t2 < 3072)      { W = wq; Wt = wTcomb;                       N = 3072; t = t2; }
        else if (t2 < 4096) { W = wg; Wt = wTcomb + (size_t)3072 * 1024; N = 1024; t = t2 - 3072; }
        else                { W = wp; Wt = wTp;                          N = 1024; t = t2 - 4096; }
        int ntiles = N >> 5;
        int nb = (t % ntiles) * 32, kb = (t / ntiles) * 32;
        int tx = threadIdx.x & 31, ty = threadIdx.x >> 5;
        #pragma unroll
        for (int i = 0; i < 4; ++i) {
            int k = kb + ty + i * 8;
            tile[ty + i * 8][tx] = to_bf16(W[(size_t)k * N + nb + tx]);
        }
        __syncthreads();
        #pragma unroll
        for (int i = 0; i < 4; ++i) {
            int n = nb + ty + i * 8;
            Wt[(size_t)n * 1024 + kb + tx] = tile[tx][ty + i * 8];
        }
    }
}

// ---------------------------------------------------------------------------
// Combined qkv+gate GEMM. BK=64 as TWO 32-k sub-buffers (each with the R4
// 64B-row-stride layout -> same bank profile), staged under ONE barrier pair:
// halves the vmcnt(0)+barrier drains vs BK=32.
// cols [0,3D): qkv from x_norm -> bf16 qkvb.
// cols [3D,4D): gate from raw x -> sigmoid -> bf16 sigb; per-row sums via
// quad shuffle-reduce + one global atomicAdd.
// ---------------------------------------------------------------------------
__global__ __launch_bounds__(256) void gemm_fused_qkvgate(const short* __restrict__ xnb,
                                                          const short* __restrict__ xb,
                                                          const short* __restrict__ Wt,
                                                          const float* __restrict__ b_qkv,
                                                          const float* __restrict__ b_gate,
                                                          short* __restrict__ qkvb,
                                                          short* __restrict__ sigb,
                                                          float* __restrict__ gmean) {
    constexpr int K = 1024;
    __shared__ short Als[2][128 * 32];   // 2 x 8 KB
    __shared__ short Bls[2][128 * 32];   // 2 x 8 KB

    const int tid  = threadIdx.x;
    const int wave = tid >> 6;
    const int lane = tid & 63;
    const int row0 = blockIdx.y * 128;
    const int col0 = blockIdx.x * 128;
    const bool isg = (col0 >= 3 * D);
    const short* A = isg ? xb : xnb;
    const int wm = (wave & 1) * 64;
    const int wn = (wave >> 1) * 64;

    f32x4 acc[4][4] = {};
    const int srow = lane >> 2;            // 0..15
    const int skk  = (lane & 3) * 8;       // 0,8,16,24 shorts
    const int fr = lane & 15;
    const int fk = (lane >> 4) * 8;

    for (int k0 = 0; k0 < K; k0 += 64) {
        __syncthreads();
        #pragma unroll
        for (int buf = 0; buf < 2; ++buf) {
            #pragma unroll
            for (int u = 0; u < 2; ++u) {
                int cchunk = wave * 2 + u;               // 0..7
                int r = cchunk * 16 + srow;
                int kc = k0 + buf * 32 + skk;
                GLOAD_LDS16(A  + (size_t)(row0 + r) * K + kc, &Als[buf][cchunk * 512]);
                GLOAD_LDS16(Wt + (size_t)(col0 + r) * K + kc, &Bls[buf][cchunk * 512]);
            }
        }
        __syncthreads();

        #pragma unroll
        for (int buf = 0; buf < 2; ++buf) {
            bf16x8 af[4], bfr[4];
            #pragma unroll
            for (int i = 0; i < 4; ++i) {
                af[i]  = *(const bf16x8*)&Als[buf][(wm + i * 16 + fr) * 32 + fk];
                bfr[i] = *(const bf16x8*)&Bls[buf][(wn + i * 16 + fr) * 32 + fk];
            }
            #pragma unroll
            for (int mi = 0; mi < 4; ++mi)
                #pragma unroll
                for (int ni = 0; ni < 4; ++ni)
                    acc[mi][ni] = __builtin_amdgcn_mfma_f32_16x16x32_bf16(af[mi], bfr[ni], acc[mi][ni], 0, 0, 0);
        }
    }

    const int ccol  = lane & 15;
    const int crow4 = (lane >> 4) * 4;
    if (!isg) {
        #pragma unroll
        for (int mi = 0; mi < 4; ++mi) {
            #pragma unroll
            for (int ni = 0; ni < 4; ++ni) {
                int col = col0 + wn + ni * 16 + ccol;
                float bv = b_qkv[col];
                #pragma unroll
                for (int r = 0; r < 4; ++r) {
                    int row = row0 + wm + mi * 16 + crow4 + r;
                    qkvb[(size_t)row * (3 * D) + col] = to_bf16(acc[mi][ni][r] + bv);
                }
            }
        }
    } else {
        #pragma unroll
        for (int mi = 0; mi < 4; ++mi) {
            #pragma unroll
            for (int r = 0; r < 4; ++r) {
                int lrow = wm + mi * 16 + crow4 + r;
                float psum = 0.0f;
                #pragma unroll
                for (int ni = 0; ni < 4; ++ni) {
                    int col = col0 + wn + ni * 16 + ccol - 3 * D;   // [0,D)
                    float v = acc[mi][ni][r] + b_gate[col];
                    float sv = 1.0f / (1.0f + __expf(-v));
                    sigb[(size_t)(row0 + lrow) * D + col] = to_bf16(sv);
                    psum += sv;
                }
                psum += __shfl_xor(psum, 1, 64);
                psum += __shfl_xor(psum, 2, 64);
                psum += __shfl_xor(psum, 4, 64);
                psum += __shfl_xor(psum, 8, 64);
                if (ccol == 0) atomicAdd(&gmean[row0 + lrow], psum);
            }
        }
    }
}

// ---------------------------------------------------------------------------
// Per-chunk state with INLINE gating on k: Sc[m][d] = sum_t Vt[m]*Kg[t][d],
// zc[d] = sum_t Kg[t][d], where Kg = elu1(k * sig/(mean+eps)).
// ---------------------------------------------------------------------------
__global__ __launch_bounds__(256) void chunk_state_mfma(const short* __restrict__ qkvb,
                                                        const short* __restrict__ sigb,
                                                        const float* __restrict__ gmean,
                                                        float* __restrict__ Sc,
                                                        float* __restrict__ zc) {
    __shared__ short Kt[DH * LS];   // [d][t] gated k
    __shared__ short Vt[DH * LS];   // [m][t]
    int idx = blockIdx.x;
    int c = idx & (NC - 1), h = (idx >> 5) & (H - 1), b = idx >> 9;
    size_t bt0 = (size_t)b * T + c * CHUNK;
    const short* kbase = qkvb + bt0 * (3 * D) + D + h * DH;
    const short* vbase = kbase + D;
    const short* sbase = sigb + bt0 * D + h * DH;
    int tid = threadIdx.x;

    #pragma unroll
    for (int l = 0; l < 2; ++l) {
        int i  = tid + l * 256;
        int t  = i >> 3;
        int d8 = (i & 7) * 8;
        float invm = 1.0f / (gmean[bt0 + t] * (1.0f / D) + 1e-5f);
        bf16x8 kv = *(const bf16x8*)(kbase + (size_t)t * (3 * D) + d8);
        bf16x8 vv = *(const bf16x8*)(vbase + (size_t)t * (3 * D) + d8);
        bf16x8 sg = *(const bf16x8*)(sbase + (size_t)t * D + d8);
        #pragma unroll
        for (int j = 0; j < 8; ++j) {
            float gn = bf2f(sg[j]) * invm;
            Kt[(d8 + j) * LS + t] = to_bf16(elu1(bf2f(kv[j]) * gn));
            Vt[(d8 + j) * LS + t] = vv[j];
        }
    }
    __syncthreads();

    const int wv = tid >> 6, lane = tid & 63;
    const int fr = lane & 15, quad = lane >> 4;
    const int fk = quad * 8, crow4 = quad * 4, ccol = lane & 15;
    const int mbase = wv * 16;

    bf16x8 af[2];
    af[0] = *(const bf16x8*)&Vt[(mbase + fr) * LS + fk];
    af[1] = *(const bf16x8*)&Vt[(mbase + fr) * LS + 32 + fk];

    f32x4 acc[4] = {};
    #pragma unroll
    for (int n = 0; n < 4; ++n) {
        #pragma unroll
        for (int ck = 0; ck < 2; ++ck) {
            bf16x8 bk = *(const bf16x8*)&Kt[(n * 16 + fr) * LS + ck * 32 + fk];
            acc[n] = __builtin_amdgcn_mfma_f32_16x16x32_bf16(af[ck], bk, acc[n], 0, 0, 0);
        }
    }

    float* Sd = Sc + (size_t)idx * (DH * DH);
    #pragma unroll
    for (int n = 0; n < 4; ++n)
        #pragma unroll
        for (int r = 0; r < 4; ++r)
            Sd[(mbase + crow4 + r) * DH + n * 16 + ccol] = acc[n][r];

    if (tid < DH) {
        float zs = 0.0f;
        for (int t = 0; t < CHUNK; ++t) zs += bf2f(Kt[tid * LS + t]);
        zc[(size_t)idx * DH + tid] = zs;
    }
}

// ---------------------------------------------------------------------------
// Exclusive prefix over chunks. Reads fp32 Sc, writes bf16 Spb; z in place.
// ---------------------------------------------------------------------------
__global__ __launch_bounds__(256) void chunk_prefix_kernel(const float* __restrict__ S,
                                                           short* __restrict__ Spb,
                                                           float* __restrict__ z) {
    int bh   = blockIdx.x >> 4;
    int part = blockIdx.x & 15;
    int e    = part * 256 + threadIdx.x;
    const float* Sb = S + (size_t)bh * NC * DH * DH;
    short* Pb = Spb + (size_t)bh * NC * DH * DH;
    float acc = 0.0f;
    for (int c = 0; c < NC; ++c) {
        size_t off = (size_t)c * DH * DH + e;
        float t = Sb[off];
        Pb[off] = to_bf16(acc);
        acc += t;
    }
    if (part == 0 && threadIdx.x < DH) {
        float* zb = z + (size_t)bh * NC * DH;
        float za = 0.0f;
        for (int c = 0; c < NC; ++c) {
            float* p = zb + c * DH + threadIdx.x;
            float t = *p; *p = za; za += t;
        }
    }
}

// ---------------------------------------------------------------------------
// Chunk attention with INLINE gating on q,k. Reads bf16 Sp. Writes bf16 out.
// ---------------------------------------------------------------------------
__global__ __launch_bounds__(256) void chunk_attn_mfma(const short* __restrict__ qkvb,
                                                       const short* __restrict__ sigb,
                                                       const float* __restrict__ gmean,
                                                       const short* __restrict__ Spb,
                                                       const float* __restrict__ zc,
                                                       short* __restrict__ attnb) {
    __shared__ short Qs[CHUNK * LS];   // [t][d] gated q
    __shared__ short Ks[CHUNK * LS];   // [s][d] gated k
    __shared__ short Vt[DH * LS];      // [m][s]
    __shared__ short Ss[DH * LS];      // [m][d]  (prefix state, bf16)
    __shared__ short As[CHUNK * LS];   // [t][s]
    __shared__ float zpL[DH];
    __shared__ float den[CHUNK];

    int idx = blockIdx.x;
    int c = idx & (NC - 1), h = (idx >> 5) & (H - 1), b = idx >> 9;
    size_t bt0 = (size_t)b * T + c * CHUNK;
    const short* qbase = qkvb + bt0 * (3 * D) + h * DH;
    const short* kbase = qbase + D;
    const short* vbase = qbase + 2 * D;
    const short* sbase = sigb + bt0 * D + h * DH;
    const short* spb = Spb + (size_t)idx * (DH * DH);
    int tid = threadIdx.x;

    #pragma unroll
    for (int l = 0; l < 2; ++l) {
        int i  = tid + l * 256;
        int t  = i >> 3;
        int d8 = (i & 7) * 8;
        float invm = 1.0f / (gmean[bt0 + t] * (1.0f / D) + 1e-5f);
        bf16x8 qv = *(const bf16x8*)(qbase + (size_t)t * (3 * D) + d8);
        bf16x8 kv = *(const bf16x8*)(kbase + (size_t)t * (3 * D) + d8);
        bf16x8 vv = *(const bf16x8*)(vbase + (size_t)t * (3 * D) + d8);
        bf16x8 sg = *(const bf16x8*)(sbase + (size_t)t * D + d8);
        bf16x8 qg, kg;
        #pragma unroll
        for (int j = 0; j < 8; ++j) {
            float gn = bf2f(sg[j]) * invm;
            qg[j] = to_bf16(elu1(bf2f(qv[j]) * gn));
            kg[j] = to_bf16(elu1(bf2f(kv[j]) * gn));
            Vt[(d8 + j) * LS + t] = vv[j];
        }
        *(bf16x8*)&Qs[t * LS + d8] = qg;
        *(bf16x8*)&Ks[t * LS + d8] = kg;
        *(bf16x8*)&Ss[t * LS + d8] = *(const bf16x8*)(spb + (size_t)i * 8);
    }
    if (tid < DH) zpL[tid] = zc[(size_t)idx * DH + tid];
    __syncthreads();

    const int wv = tid >> 6, lane = tid & 63;
    const int fr = lane & 15, quad = lane >> 4;
    const int fk = quad * 8, crow4 = quad * 4, ccol = lane & 15;
    const int tbase = wv * 16;

    bf16x8 aq[2];
    aq[0] = *(const bf16x8*)&Qs[(tbase + fr) * LS + fk];
    aq[1] = *(const bf16x8*)&Qs[(tbase + fr) * LS + 32 + fk];

    // scores C[t][s] = q_t . k_s
    f32x4 accs[4] = {};
    #pragma unroll
    for (int n = 0; n < 4; ++n) {
        #pragma unroll
        for (int ck = 0; ck < 2; ++ck) {
            bf16x8 bk = *(const bf16x8*)&Ks[(n * 16 + fr) * LS + ck * 32 + fk];
            accs[n] = __builtin_amdgcn_mfma_f32_16x16x32_bf16(aq[ck], bk, accs[n], 0, 0, 0);
        }
    }

    float part[4] = {0.f, 0.f, 0.f, 0.f};
    #pragma unroll
    for (int n = 0; n < 4; ++n) {
        #pragma unroll
        for (int r = 0; r < 4; ++r) {
            int tt = tbase + crow4 + r;
            int ss = n * 16 + ccol;
            float v = (ss <= tt) ? accs[n][r] : 0.0f;
            part[r] += v;
            As[tt * LS + ss] = to_bf16(v);
        }
    }
    #pragma unroll
    for (int r = 0; r < 4; ++r) {
        part[r] += __shfl_xor(part[r], 1, 64);
        part[r] += __shfl_xor(part[r], 2, 64);
        part[r] += __shfl_xor(part[r], 4, 64);
        part[r] += __shfl_xor(part[r], 8, 64);
    }
    if (fr == 0) {
        #pragma unroll
        for (int r = 0; r < 4; ++r) den[tbase + crow4 + r] = part[r];
    }
    __syncthreads();

    if (tid < CHUNK) {
        float qz = 0.0f;
        #pragma unroll 8
        for (int d = 0; d < DH; ++d) qz += bf2f(Qs[tid * LS + d]) * zpL[d];
        den[tid] += qz + 1e-5f;
    }

    // out C[t][m] = Q @ Sp + A @ V
    f32x4 acco[4] = {};
    #pragma unroll
    for (int m4 = 0; m4 < 4; ++m4) {
        #pragma unroll
        for (int ck = 0; ck < 2; ++ck) {
            bf16x8 bs = *(const bf16x8*)&Ss[(m4 * 16 + fr) * LS + ck * 32 + fk];
            acco[m4] = __builtin_amdgcn_mfma_f32_16x16x32_bf16(aq[ck], bs, acco[m4], 0, 0, 0);
        }
    }
    bf16x8 aa[2];
    aa[0] = *(const bf16x8*)&As[(tbase + fr) * LS + fk];
    aa[1] = *(const bf16x8*)&As[(tbase + fr) * LS + 32 + fk];
    #pragma unroll
    for (int m4 = 0; m4 < 4; ++m4) {
        #pragma unroll
        for (int ck = 0; ck < 2; ++ck) {
            bf16x8 bv = *(const bf16x8*)&Vt[(m4 * 16 + fr) * LS + ck * 32 + fk];
            acco[m4] = __builtin_amdgcn_mfma_f32_16x16x32_bf16(aa[ck], bv, acco[m4], 0, 0, 0);
        }
    }
    __syncthreads();

    short* obase = attnb + bt0 * D + h * DH;
    #pragma unroll
    for (int r = 0; r < 4; ++r) {
        int tt = tbase + crow4 + r;
        float rv = 1.0f / den[tt];
        #pragma unroll
        for (int m4 = 0; m4 < 4; ++m4)
            obase[(size_t)tt * D + m4 * 16 + ccol] = to_bf16(acco[m4][r] * rv);
    }
}

// ---------------------------------------------------------------------------
// Proj GEMM, BK=64 via two 32-k sub-buffers (one barrier pair per 64-k).
// C[4096][1024] fp32 = A @ Bt^T + bias. 64x128 tile, 512 blocks.
// ---------------------------------------------------------------------------
__global__ __launch_bounds__(256) void gemm_proj64(const short* __restrict__ A,
                                                   const short* __restrict__ Bt,
                                                   const float* __restrict__ bias,
                                                   float* __restrict__ C) {
    constexpr int K = 1024, N = 1024;
    __shared__ short Als[2][64 * 32];    // 2 x 4 KB
    __shared__ short Bls[2][128 * 32];   // 2 x 8 KB

    const int tid  = threadIdx.x;
    const int wave = tid >> 6;
    const int lane = tid & 63;
    const int row0 = blockIdx.y * 64;
    const int col0 = blockIdx.x * 128;
    const int wn = wave * 32;

    f32x4 acc[4][2] = {};
    const int srow = lane >> 2;
    const int skk  = (lane & 3) * 8;
    const int fr = lane & 15;
    const int fk = (lane >> 4) * 8;

    for (int k0 = 0; k0 < K; k0 += 64) {
        __syncthreads();
        #pragma unroll
        for (int u = 0; u < 6; ++u) {
            int cc = wave * 6 + u;   // 0..23: [0,8) A (2 bufs x 4 chunks), [8,24) B (2 bufs x 8 chunks)
            if (cc < 8) {
                int buf = cc >> 2, ch = cc & 3;
                int r = ch * 16 + srow;
                GLOAD_LDS16(A + (size_t)(row0 + r) * K + k0 + buf * 32 + skk, &Als[buf][ch * 512]);
            } else {
                int d2 = cc - 8;
                int buf = d2 >> 3, ch = d2 & 7;
                int r = ch * 16 + srow;
                GLOAD_LDS16(Bt + (size_t)(col0 + r) * K + k0 + buf * 32 + skk, &Bls[buf][ch * 512]);
            }
        }
        __syncthreads();

        #pragma unroll
        for (int buf = 0; buf < 2; ++buf) {
            bf16x8 af[4], bfr[2];
            #pragma unroll
            for (int i = 0; i < 4; ++i)
                af[i] = *(const bf16x8*)&Als[buf][(i * 16 + fr) * 32 + fk];
            #pragma unroll
            for (int j = 0; j < 2; ++j)
                bfr[j] = *(const bf16x8*)&Bls[buf][(wn + j * 16 + fr) * 32 + fk];
            #pragma unroll
            for (int mi = 0; mi < 4; ++mi)
                #pragma unroll
                for (int ni = 0; ni < 2; ++ni)
                    acc[mi][ni] = __builtin_amdgcn_mfma_f32_16x16x32_bf16(af[mi], bfr[ni], acc[mi][ni], 0, 0, 0);
        }
    }

    const int ccol  = lane & 15;
    const int crow4 = (lane >> 4) * 4;
    #pragma unroll
    for (int mi = 0; mi < 4; ++mi) {
        #pragma unroll
        for (int ni = 0; ni < 2; ++ni) {
            int col = col0 + wn + ni * 16 + ccol;
            float bv = bias[col];
            #pragma unroll
            for (int r = 0; r < 4; ++r) {
                int row = row0 + mi * 16 + crow4 + r;
                C[(size_t)row * N + col] = acc[mi][ni][r] + bv;
            }
        }
    }
}

// ---------------------------------------------------------------------------
extern "C" void kernel_launch(void* const* d_in, const int* in_sizes, int n_in,
                              void* d_out, int out_size, void* d_ws, size_t ws_size,
                              hipStream_t stream) {
    const float* x      = (const float*)d_in[0];
    const float* ln_g   = (const float*)d_in[1];
    const float* ln_b   = (const float*)d_in[2];
    const float* w_qkv  = (const float*)d_in[3];
    const float* b_qkv  = (const float*)d_in[4];
    const float* w_gate = (const float*)d_in[5];
    const float* b_gate = (const float*)d_in[6];
    const float* w_proj = (const float*)d_in[7];
    const float* b_proj = (const float*)d_in[8];
    float* out = (float*)d_out;

    short* xnb   = (short*)d_ws;                       // BT*D bf16 (8 MB)  [dead after GEMM]
    short* xb    = xnb + (size_t)BT * D;               // BT*D bf16 (8 MB)  [dead after GEMM]
    short* wTc   = xb + (size_t)BT * D;                // 4096*1024 bf16 (8 MB) [dead after GEMM]
    short* wTp   = wTc + (size_t)4096 * 1024;          // D*D bf16 (2 MB)
    short* qkvb  = wTp + (size_t)D * D;                // BT*3D bf16 (24 MB)
    short* sigb  = qkvb + (size_t)BT * 3 * D;          // BT*D bf16 (8 MB)
    short* attnb = sigb + (size_t)BT * D;              // BT*D bf16 (8 MB)
    float* zc    = (float*)(attnb + (size_t)BT * D);   // Bb*H*NC*DH fp32 (256 KB)
    float* gmean = zc + (size_t)Bb * H * NC * DH;      // BT fp32 (16 KB)
    float* Sc    = (float*)xnb;                        // Bb*H*NC*DH*DH fp32 (16 MB), aliases xnb+xb
    short* Spb   = wTc;                                // BT*D bf16 (8 MB), aliases wTc

    pre_kernel<<<BT + 5120, 256, 0, stream>>>(x, ln_g, ln_b, w_qkv, w_gate, w_proj,
                                              xnb, xb, wTc, wTp, gmean);
    gemm_fused_qkvgate<<<dim3(32, 32), 256, 0, stream>>>(
        xnb, xb, wTc, b_qkv, b_gate, qkvb, sigb, gmean);
    chunk_state_mfma<<<Bb * H * NC, 256, 0, stream>>>(qkvb, sigb, gmean, Sc, zc);
    chunk_prefix_kernel<<<Bb * H * 16, 256, 0, stream>>>(Sc, Spb, zc);
    chunk_attn_mfma<<<Bb * H * NC, 256, 0, stream>>>(qkvb, sigb, gmean, Spb, zc, attnb);
    gemm_proj64<<<dim3(D / 128, BT / 64), 256, 0, stream>>>(attnb, wTp, b_proj, out);
}

// Round 9
// 205.146 us; speedup vs baseline: 1.2093x; 1.0026x over previous
//
#include <hip/hip_runtime.h>
#include <math.h>

// Problem constants
constexpr int D      = 1024;
constexpr int H      = 16;
constexpr int DH     = 64;
constexpr int Bb     = 2;
constexpr int T      = 2048;
constexpr int BT     = Bb * T;       // 4096
constexpr int CHUNK  = 64;
constexpr int NC     = T / CHUNK;    // 32
constexpr int LS     = 72;           // LDS row stride (shorts) for chunk kernels

typedef __attribute__((ext_vector_type(8))) short bf16x8;
typedef __attribute__((ext_vector_type(4))) float f32x4;

#define GLOAD_LDS16(gp, lp) \
    __builtin_amdgcn_global_load_lds((const __attribute__((address_space(1))) void*)(gp), \
                                     (__attribute__((address_space(3))) void*)(lp), 16, 0, 0)

__device__ __forceinline__ short to_bf16(float f) {
    unsigned u = __float_as_uint(f);
    unsigned r = (u + 0x7fffu + ((u >> 16) & 1u)) >> 16;
    return (short)r;
}
__device__ __forceinline__ float bf2f(short s) {
    return __uint_as_float(((unsigned)(unsigned short)s) << 16);
}

__device__ __forceinline__ float block_sum_256(float v, float* sbuf) {
    #pragma unroll
    for (int off = 32; off > 0; off >>= 1) v += __shfl_down(v, off, 64);
    int lane = threadIdx.x & 63;
    int wid  = threadIdx.x >> 6;
    if (lane == 0) sbuf[wid] = v;
    __syncthreads();
    float r = (threadIdx.x < 4) ? sbuf[threadIdx.x] : 0.0f;
    r += __shfl_down(r, 2, 64);
    r += __shfl_down(r, 1, 64);
    if (threadIdx.x == 0) sbuf[0] = r;
    __syncthreads();
    float outv = sbuf[0];
    __syncthreads();
    return outv;
}

__device__ __forceinline__ float elu1(float x) {
    return x > 0.0f ? x + 1.0f : __expf(x);
}

// ---------------------------------------------------------------------------
// Merged prologue: blocks [0,BT): LayerNorm + zero gmean[row];
// [BT, BT+5120): three weight transposes (fp32 -> bf16, [K,N] -> [N,K]).
// ---------------------------------------------------------------------------
__global__ __launch_bounds__(256) void pre_kernel(const float* __restrict__ x,
                                                  const float* __restrict__ g,
                                                  const float* __restrict__ b,
                                                  const float* __restrict__ wq,
                                                  const float* __restrict__ wg,
                                                  const float* __restrict__ wp,
                                                  short* __restrict__ ynb,
                                                  short* __restrict__ xbb,
                                                  short* __restrict__ wTcomb,
                                                  short* __restrict__ wTp,
                                                  float* __restrict__ gmean) {
    __shared__ float sbuf[4];
    __shared__ short tile[32][33];
    int bid = blockIdx.x;
    if (bid < BT) {
        int row = bid;
        if (threadIdx.x == 0) gmean[row] = 0.0f;
        const float* xr = x + (size_t)row * D;
        int c = threadIdx.x * 4;
        float4 xv = *(const float4*)(xr + c);
        float mu = block_sum_256(xv.x + xv.y + xv.z + xv.w, sbuf) * (1.0f / D);
        float d0 = xv.x - mu, d1 = xv.y - mu, d2 = xv.z - mu, d3 = xv.w - mu;
        float var = block_sum_256(d0*d0 + d1*d1 + d2*d2 + d3*d3, sbuf) * (1.0f / D);
        float rstd = rsqrtf(var + 1e-5f);
        float4 gv = *(const float4*)(g + c);
        float4 bv = *(const float4*)(b + c);
        short4 o, xo;
        o.x = to_bf16(d0 * rstd * gv.x + bv.x);
        o.y = to_bf16(d1 * rstd * gv.y + bv.y);
        o.z = to_bf16(d2 * rstd * gv.z + bv.z);
        o.w = to_bf16(d3 * rstd * gv.w + bv.w);
        xo.x = to_bf16(xv.x); xo.y = to_bf16(xv.y);
        xo.z = to_bf16(xv.z); xo.w = to_bf16(xv.w);
        *(short4*)(ynb + (size_t)row * D + c) = o;
        *(short4*)(xbb + (size_t)row * D + c) = xo;
    } else {
        int t2 = bid - BT;
        const float* W; short* Wt; int N; int t;
        if (t2 < 3072)      { W = wq; Wt = wTcomb;                       N = 3072; t = t2; }
        else if (t2 < 4096) { W = wg; Wt = wTcomb + (size_t)3072 * 1024; N = 1024; t = t2 - 3072; }
        else                { W = wp; Wt = wTp;                          N = 1024; t = t2 - 4096; }
        int ntiles = N >> 5;
        int nb = (t % ntiles) * 32, kb = (t / ntiles) * 32;
        int tx = threadIdx.x & 31, ty = threadIdx.x >> 5;
        #pragma unroll
        for (int i = 0; i < 4; ++i) {
            int k = kb + ty + i * 8;
            tile[ty + i * 8][tx] = to_bf16(W[(size_t)k * N + nb + tx]);
        }
        __syncthreads();
        #pragma unroll
        for (int i = 0; i < 4; ++i) {
            int n = nb + ty + i * 8;
            Wt[(size_t)n * 1024 + kb + tx] = tile[tx][ty + i * 8];
        }
    }
}

// ---------------------------------------------------------------------------
// Combined qkv+gate GEMM, BK=32 (R7 body) + XCD-rectangle swizzle:
// 1D grid of 1024; xcd = bid&7 owns a 16-row x 8-col rectangle of 128-tiles
// so each XCD's L2 works on a ~6 MB slab instead of the full 24 MB.
// cols [0,3D): qkv from x_norm -> bf16 qkvb.
// cols [3D,4D): gate from raw x -> sigmoid -> bf16 sigb; per-row sums via
// quad shuffle-reduce + one global atomicAdd into gmean.
// ---------------------------------------------------------------------------
__global__ __launch_bounds__(256) void gemm_fused_qkvgate(const short* __restrict__ xnb,
                                                          const short* __restrict__ xb,
                                                          const short* __restrict__ Wt,
                                                          const float* __restrict__ b_qkv,
                                                          const float* __restrict__ b_gate,
                                                          short* __restrict__ qkvb,
                                                          short* __restrict__ sigb,
                                                          float* __restrict__ gmean) {
    constexpr int BK = 32, K = 1024;
    __shared__ short Als[128 * BK];   // 8 KB
    __shared__ short Bls[128 * BK];   // 8 KB

    // XCD-rectangle swizzle (bid -> XCD is round-robin, m09)
    const int bid   = blockIdx.x;
    const int xcd   = bid & 7;
    const int local = bid >> 3;            // 0..127
    const int cx = xcd & 3, ry = xcd >> 2; // 4 col-slabs x 2 row-slabs
    const int lx = local & 7, ly = local >> 3;
    const int bxx = cx * 8 + lx;           // 0..31 col-block
    const int byy = ry * 16 + ly;          // 0..31 row-block

    const int tid  = threadIdx.x;
    const int wave = tid >> 6;
    const int lane = tid & 63;
    const int row0 = byy * 128;
    const int col0 = bxx * 128;
    const bool isg = (col0 >= 3 * D);
    const short* A = isg ? xb : xnb;
    const int wm = (wave & 1) * 64;
    const int wn = (wave >> 1) * 64;

    f32x4 acc[4][4] = {};
    const int srow = lane >> 2;            // 0..15
    const int skk  = (lane & 3) * 8;       // 0,8,16,24
    const int fr = lane & 15;
    const int fk = (lane >> 4) * 8;

    for (int k0 = 0; k0 < K; k0 += BK) {
        __syncthreads();
        #pragma unroll
        for (int u = 0; u < 2; ++u) {
            int cchunk = wave * 2 + u;
            int r = cchunk * 16 + srow;
            GLOAD_LDS16(A  + (size_t)(row0 + r) * K + k0 + skk, &Als[cchunk * 512]);
            GLOAD_LDS16(Wt + (size_t)(col0 + r) * K + k0 + skk, &Bls[cchunk * 512]);
        }
        __syncthreads();

        bf16x8 af[4], bfr[4];
        #pragma unroll
        for (int i = 0; i < 4; ++i) {
            af[i]  = *(const bf16x8*)&Als[(wm + i * 16 + fr) * BK + fk];
            bfr[i] = *(const bf16x8*)&Bls[(wn + i * 16 + fr) * BK + fk];
        }
        #pragma unroll
        for (int mi = 0; mi < 4; ++mi)
            #pragma unroll
            for (int ni = 0; ni < 4; ++ni)
                acc[mi][ni] = __builtin_amdgcn_mfma_f32_16x16x32_bf16(af[mi], bfr[ni], acc[mi][ni], 0, 0, 0);
    }

    const int ccol  = lane & 15;
    const int crow4 = (lane >> 4) * 4;
    if (!isg) {
        #pragma unroll
        for (int mi = 0; mi < 4; ++mi) {
            #pragma unroll
            for (int ni = 0; ni < 4; ++ni) {
                int col = col0 + wn + ni * 16 + ccol;
                float bv = b_qkv[col];
                #pragma unroll
                for (int r = 0; r < 4; ++r) {
                    int row = row0 + wm + mi * 16 + crow4 + r;
                    qkvb[(size_t)row * (3 * D) + col] = to_bf16(acc[mi][ni][r] + bv);
                }
            }
        }
    } else {
        #pragma unroll
        for (int mi = 0; mi < 4; ++mi) {
            #pragma unroll
            for (int r = 0; r < 4; ++r) {
                int lrow = wm + mi * 16 + crow4 + r;
                float psum = 0.0f;
                #pragma unroll
                for (int ni = 0; ni < 4; ++ni) {
                    int col = col0 + wn + ni * 16 + ccol - 3 * D;   // [0,D)
                    float v = acc[mi][ni][r] + b_gate[col];
                    float sv = 1.0f / (1.0f + __expf(-v));
                    sigb[(size_t)(row0 + lrow) * D + col] = to_bf16(sv);
                    psum += sv;
                }
                psum += __shfl_xor(psum, 1, 64);
                psum += __shfl_xor(psum, 2, 64);
                psum += __shfl_xor(psum, 4, 64);
                psum += __shfl_xor(psum, 8, 64);
                if (ccol == 0) atomicAdd(&gmean[row0 + lrow], psum);
            }
        }
    }
}

// ---------------------------------------------------------------------------
// Per-chunk state with INLINE gating on k: Sc[m][d] = sum_t Vt[m]*Kg[t][d],
// zc[d] = sum_t Kg[t][d], where Kg = elu1(k * sig/(mean+eps)).
// ---------------------------------------------------------------------------
__global__ __launch_bounds__(256) void chunk_state_mfma(const short* __restrict__ qkvb,
                                                        const short* __restrict__ sigb,
                                                        const float* __restrict__ gmean,
                                                        float* __restrict__ Sc,
                                                        float* __restrict__ zc) {
    __shared__ short Kt[DH * LS];   // [d][t] gated k
    __shared__ short Vt[DH * LS];   // [m][t]
    int idx = blockIdx.x;
    int c = idx & (NC - 1), h = (idx >> 5) & (H - 1), b = idx >> 9;
    size_t bt0 = (size_t)b * T + c * CHUNK;
    const short* kbase = qkvb + bt0 * (3 * D) + D + h * DH;
    const short* vbase = kbase + D;
    const short* sbase = sigb + bt0 * D + h * DH;
    int tid = threadIdx.x;

    #pragma unroll
    for (int l = 0; l < 2; ++l) {
        int i  = tid + l * 256;
        int t  = i >> 3;
        int d8 = (i & 7) * 8;
        float invm = 1.0f / (gmean[bt0 + t] * (1.0f / D) + 1e-5f);
        bf16x8 kv = *(const bf16x8*)(kbase + (size_t)t * (3 * D) + d8);
        bf16x8 vv = *(const bf16x8*)(vbase + (size_t)t * (3 * D) + d8);
        bf16x8 sg = *(const bf16x8*)(sbase + (size_t)t * D + d8);
        #pragma unroll
        for (int j = 0; j < 8; ++j) {
            float gn = bf2f(sg[j]) * invm;
            Kt[(d8 + j) * LS + t] = to_bf16(elu1(bf2f(kv[j]) * gn));
            Vt[(d8 + j) * LS + t] = vv[j];
        }
    }
    __syncthreads();

    const int wv = tid >> 6, lane = tid & 63;
    const int fr = lane & 15, quad = lane >> 4;
    const int fk = quad * 8, crow4 = quad * 4, ccol = lane & 15;
    const int mbase = wv * 16;

    bf16x8 af[2];
    af[0] = *(const bf16x8*)&Vt[(mbase + fr) * LS + fk];
    af[1] = *(const bf16x8*)&Vt[(mbase + fr) * LS + 32 + fk];

    f32x4 acc[4] = {};
    #pragma unroll
    for (int n = 0; n < 4; ++n) {
        #pragma unroll
        for (int ck = 0; ck < 2; ++ck) {
            bf16x8 bk = *(const bf16x8*)&Kt[(n * 16 + fr) * LS + ck * 32 + fk];
            acc[n] = __builtin_amdgcn_mfma_f32_16x16x32_bf16(af[ck], bk, acc[n], 0, 0, 0);
        }
    }

    float* Sd = Sc + (size_t)idx * (DH * DH);
    #pragma unroll
    for (int n = 0; n < 4; ++n)
        #pragma unroll
        for (int r = 0; r < 4; ++r)
            Sd[(mbase + crow4 + r) * DH + n * 16 + ccol] = acc[n][r];

    if (tid < DH) {
        float zs = 0.0f;
        for (int t = 0; t < CHUNK; ++t) zs += bf2f(Kt[tid * LS + t]);
        zc[(size_t)idx * DH + tid] = zs;
    }
}

// ---------------------------------------------------------------------------
// Exclusive prefix over chunks. Reads fp32 Sc, writes bf16 Spb; z in place.
// ---------------------------------------------------------------------------
__global__ __launch_bounds__(256) void chunk_prefix_kernel(const float* __restrict__ S,
                                                           short* __restrict__ Spb,
                                                           float* __restrict__ z) {
    int bh   = blockIdx.x >> 4;
    int part = blockIdx.x & 15;
    int e    = part * 256 + threadIdx.x;
    const float* Sb = S + (size_t)bh * NC * DH * DH;
    short* Pb = Spb + (size_t)bh * NC * DH * DH;
    float acc = 0.0f;
    for (int c = 0; c < NC; ++c) {
        size_t off = (size_t)c * DH * DH + e;
        float t = Sb[off];
        Pb[off] = to_bf16(acc);
        acc += t;
    }
    if (part == 0 && threadIdx.x < DH) {
        float* zb = z + (size_t)bh * NC * DH;
        float za = 0.0f;
        for (int c = 0; c < NC; ++c) {
            float* p = zb + c * DH + threadIdx.x;
            float t = *p; *p = za; za += t;
        }
    }
}

// ---------------------------------------------------------------------------
// Chunk attention with INLINE gating on q,k. As aliases Ks (dead after scores)
// -> LDS ~37 KB -> 4 blocks/CU (was 3). Reads bf16 Sp. Writes bf16 out.
// ---------------------------------------------------------------------------
__global__ __launch_bounds__(256) void chunk_attn_mfma(const short* __restrict__ qkvb,
                                                       const short* __restrict__ sigb,
                                                       const float* __restrict__ gmean,
                                                       const short* __restrict__ Spb,
                                                       const float* __restrict__ zc,
                                                       short* __restrict__ attnb) {
    __shared__ short Qs[CHUNK * LS];   // [t][d] gated q
    __shared__ short Ks[CHUNK * LS];   // [s][d] gated k; reused as As[t][s]
    __shared__ short Vt[DH * LS];      // [m][s]
    __shared__ short Ss[DH * LS];      // [m][d]  (prefix state, bf16)
    __shared__ float zpL[DH];
    __shared__ float den[CHUNK];
    short* As = Ks;                    // alias: Ks dead after scores

    int idx = blockIdx.x;
    int c = idx & (NC - 1), h = (idx >> 5) & (H - 1), b = idx >> 9;
    size_t bt0 = (size_t)b * T + c * CHUNK;
    const short* qbase = qkvb + bt0 * (3 * D) + h * DH;
    const short* kbase = qbase + D;
    const short* vbase = qbase + 2 * D;
    const short* sbase = sigb + bt0 * D + h * DH;
    const short* spb = Spb + (size_t)idx * (DH * DH);
    int tid = threadIdx.x;

    #pragma unroll
    for (int l = 0; l < 2; ++l) {
        int i  = tid + l * 256;
        int t  = i >> 3;
        int d8 = (i & 7) * 8;
        float invm = 1.0f / (gmean[bt0 + t] * (1.0f / D) + 1e-5f);
        bf16x8 qv = *(const bf16x8*)(qbase + (size_t)t * (3 * D) + d8);
        bf16x8 kv = *(const bf16x8*)(kbase + (size_t)t * (3 * D) + d8);
        bf16x8 vv = *(const bf16x8*)(vbase + (size_t)t * (3 * D) + d8);
        bf16x8 sg = *(const bf16x8*)(sbase + (size_t)t * D + d8);
        bf16x8 qg, kg;
        #pragma unroll
        for (int j = 0; j < 8; ++j) {
            float gn = bf2f(sg[j]) * invm;
            qg[j] = to_bf16(elu1(bf2f(qv[j]) * gn));
            kg[j] = to_bf16(elu1(bf2f(kv[j]) * gn));
            Vt[(d8 + j) * LS + t] = vv[j];
        }
        *(bf16x8*)&Qs[t * LS + d8] = qg;
        *(bf16x8*)&Ks[t * LS + d8] = kg;
        *(bf16x8*)&Ss[t * LS + d8] = *(const bf16x8*)(spb + (size_t)i * 8);
    }
    if (tid < DH) zpL[tid] = zc[(size_t)idx * DH + tid];
    __syncthreads();

    const int wv = tid >> 6, lane = tid & 63;
    const int fr = lane & 15, quad = lane >> 4;
    const int fk = quad * 8, crow4 = quad * 4, ccol = lane & 15;
    const int tbase = wv * 16;

    bf16x8 aq[2];
    aq[0] = *(const bf16x8*)&Qs[(tbase + fr) * LS + fk];
    aq[1] = *(const bf16x8*)&Qs[(tbase + fr) * LS + 32 + fk];

    // scores C[t][s] = q_t . k_s
    f32x4 accs[4] = {};
    #pragma unroll
    for (int n = 0; n < 4; ++n) {
        #pragma unroll
        for (int ck = 0; ck < 2; ++ck) {
            bf16x8 bk = *(const bf16x8*)&Ks[(n * 16 + fr) * LS + ck * 32 + fk];
            accs[n] = __builtin_amdgcn_mfma_f32_16x16x32_bf16(aq[ck], bk, accs[n], 0, 0, 0);
        }
    }
    __syncthreads();   // all Ks reads complete before As overwrites it

    float part[4] = {0.f, 0.f, 0.f, 0.f};
    #pragma unroll
    for (int n = 0; n < 4; ++n) {
        #pragma unroll
        for (int r = 0; r < 4; ++r) {
            int tt = tbase + crow4 + r;
            int ss = n * 16 + ccol;
            float v = (ss <= tt) ? accs[n][r] : 0.0f;
            part[r] += v;
            As[tt * LS + ss] = to_bf16(v);
        }
    }
    #pragma unroll
    for (int r = 0; r < 4; ++r) {
        part[r] += __shfl_xor(part[r], 1, 64);
        part[r] += __shfl_xor(part[r], 2, 64);
        part[r] += __shfl_xor(part[r], 4, 64);
        part[r] += __shfl_xor(part[r], 8, 64);
    }
    if (fr == 0) {
        #pragma unroll
        for (int r = 0; r < 4; ++r) den[tbase + crow4 + r] = part[r];
    }
    __syncthreads();

    if (tid < CHUNK) {
        float qz = 0.0f;
        #pragma unroll 8
        for (int d = 0; d < DH; ++d) qz += bf2f(Qs[tid * LS + d]) * zpL[d];
        den[tid] += qz + 1e-5f;
    }

    // out C[t][m] = Q @ Sp + A @ V
    f32x4 acco[4] = {};
    #pragma unroll
    for (int m4 = 0; m4 < 4; ++m4) {
        #pragma unroll
        for (int ck = 0; ck < 2; ++ck) {
            bf16x8 bs = *(const bf16x8*)&Ss[(m4 * 16 + fr) * LS + ck * 32 + fk];
            acco[m4] = __builtin_amdgcn_mfma_f32_16x16x32_bf16(aq[ck], bs, acco[m4], 0, 0, 0);
        }
    }
    bf16x8 aa[2];
    aa[0] = *(const bf16x8*)&As[(tbase + fr) * LS + fk];
    aa[1] = *(const bf16x8*)&As[(tbase + fr) * LS + 32 + fk];
    #pragma unroll
    for (int m4 = 0; m4 < 4; ++m4) {
        #pragma unroll
        for (int ck = 0; ck < 2; ++ck) {
            bf16x8 bv = *(const bf16x8*)&Vt[(m4 * 16 + fr) * LS + ck * 32 + fk];
            acco[m4] = __builtin_amdgcn_mfma_f32_16x16x32_bf16(aa[ck], bv, acco[m4], 0, 0, 0);
        }
    }
    __syncthreads();

    short* obase = attnb + bt0 * D + h * DH;
    #pragma unroll
    for (int r = 0; r < 4; ++r) {
        int tt = tbase + crow4 + r;
        float rv = 1.0f / den[tt];
        #pragma unroll
        for (int m4 = 0; m4 < 4; ++m4)
            obase[(size_t)tt * D + m4 * 16 + ccol] = to_bf16(acco[m4][r] * rv);
    }
}

// ---------------------------------------------------------------------------
// Proj GEMM, BK=32 + XCD-rectangle swizzle (2-col x 32-row rectangles).
// C[4096][1024] fp32 = A @ Bt^T + bias. 64x128 tile, 1D grid 512.
// ---------------------------------------------------------------------------
__global__ __launch_bounds__(256) void gemm_proj64(const short* __restrict__ A,
                                                   const short* __restrict__ Bt,
                                                   const float* __restrict__ bias,
                                                   float* __restrict__ C) {
    constexpr int BK = 32, K = 1024, N = 1024;
    __shared__ short Als[64 * BK];    // 4 KB
    __shared__ short Bls[128 * BK];   // 8 KB

    const int bid   = blockIdx.x;
    const int xcd   = bid & 7;
    const int local = bid >> 3;            // 0..63
    const int cx = xcd & 3, ry = xcd >> 2; // 4 col-slabs x 2 row-slabs
    const int lx = local & 1, ly = local >> 1;
    const int bxx = cx * 2 + lx;           // 0..7 col-block
    const int byy = ry * 32 + ly;          // 0..63 row-block

    const int tid  = threadIdx.x;
    const int wave = tid >> 6;
    const int lane = tid & 63;
    const int row0 = byy * 64;
    const int col0 = bxx * 128;
    const int wn = wave * 32;

    f32x4 acc[4][2] = {};
    const int srow = lane >> 2;
    const int skk  = (lane & 3) * 8;
    const int fr = lane & 15;
    const int fk = (lane >> 4) * 8;

    for (int k0 = 0; k0 < K; k0 += BK) {
        __syncthreads();
        #pragma unroll
        for (int u = 0; u < 3; ++u) {
            int cc = wave * 3 + u;   // 0..11; 0..3 -> A chunks, 4..11 -> B chunks
            if (cc < 4) {
                int r = cc * 16 + srow;
                GLOAD_LDS16(A + (size_t)(row0 + r) * K + k0 + skk, &Als[cc * 512]);
            } else {
                int c2 = cc - 4;
                int r = c2 * 16 + srow;
                GLOAD_LDS16(Bt + (size_t)(col0 + r) * K + k0 + skk, &Bls[c2 * 512]);
            }
        }
        __syncthreads();

        bf16x8 af[4], bfr[2];
        #pragma unroll
        for (int i = 0; i < 4; ++i)
            af[i] = *(const bf16x8*)&Als[(i * 16 + fr) * BK + fk];
        #pragma unroll
        for (int j = 0; j < 2; ++j)
            bfr[j] = *(const bf16x8*)&Bls[(wn + j * 16 + fr) * BK + fk];
        #pragma unroll
        for (int mi = 0; mi < 4; ++mi)
            #pragma unroll
            for (int ni = 0; ni < 2; ++ni)
                acc[mi][ni] = __builtin_amdgcn_mfma_f32_16x16x32_bf16(af[mi], bfr[ni], acc[mi][ni], 0, 0, 0);
    }

    const int ccol  = lane & 15;
    const int crow4 = (lane >> 4) * 4;
    #pragma unroll
    for (int mi = 0; mi < 4; ++mi) {
        #pragma unroll
        for (int ni = 0; ni < 2; ++ni) {
            int col = col0 + wn + ni * 16 + ccol;
            float bv = bias[col];
            #pragma unroll
            for (int r = 0; r < 4; ++r) {
                int row = row0 + mi * 16 + crow4 + r;
                C[(size_t)row * N + col] = acc[mi][ni][r] + bv;
            }
        }
    }
}

// ---------------------------------------------------------------------------
extern "C" void kernel_launch(void* const* d_in, const int* in_sizes, int n_in,
                              void* d_out, int out_size, void* d_ws, size_t ws_size,
                              hipStream_t stream) {
    const float* x      = (const float*)d_in[0];
    const float* ln_g   = (const float*)d_in[1];
    const float* ln_b   = (const float*)d_in[2];
    const float* w_qkv  = (const float*)d_in[3];
    const float* b_qkv  = (const float*)d_in[4];
    const float* w_gate = (const float*)d_in[5];
    const float* b_gate = (const float*)d_in[6];
    const float* w_proj = (const float*)d_in[7];
    const float* b_proj = (const float*)d_in[8];
    float* out = (float*)d_out;

    short* xnb   = (short*)d_ws;                       // BT*D bf16 (8 MB)  [dead after GEMM]
    short* xb    = xnb + (size_t)BT * D;               // BT*D bf16 (8 MB)  [dead after GEMM]
    short* wTc   = xb + (size_t)BT * D;                // 4096*1024 bf16 (8 MB) [dead after GEMM]
    short* wTp   = wTc + (size_t)4096 * 1024;          // D*D bf16 (2 MB)
    short* qkvb  = wTp + (size_t)D * D;                // BT*3D bf16 (24 MB)
    short* sigb  = qkvb + (size_t)BT * 3 * D;          // BT*D bf16 (8 MB)
    short* attnb = sigb + (size_t)BT * D;              // BT*D bf16 (8 MB)
    float* zc    = (float*)(attnb + (size_t)BT * D);   // Bb*H*NC*DH fp32 (256 KB)
    float* gmean = zc + (size_t)Bb * H * NC * DH;      // BT fp32 (16 KB)
    float* Sc    = (float*)xnb;                        // Bb*H*NC*DH*DH fp32 (16 MB), aliases xnb+xb
    short* Spb   = wTc;                                // BT*D bf16 (8 MB), aliases wTc

    pre_kernel<<<BT + 5120, 256, 0, stream>>>(x, ln_g, ln_b, w_qkv, w_gate, w_proj,
                                              xnb, xb, wTc, wTp, gmean);
    gemm_fused_qkvgate<<<1024, 256, 0, stream>>>(
        xnb, xb, wTc, b_qkv, b_gate, qkvb, sigb, gmean);
    chunk_state_mfma<<<Bb * H * NC, 256, 0, stream>>>(qkvb, sigb, gmean, Sc, zc);
    chunk_prefix_kernel<<<Bb * H * 16, 256, 0, stream>>>(Sc, Spb, zc);
    chunk_attn_mfma<<<Bb * H * NC, 256, 0, stream>>>(qkvb, sigb, gmean, Spb, zc, attnb);
    gemm_proj64<<<512, 256, 0, stream>>>(attnb, wTp, b_proj, out);
}